// Round 9
// baseline (277.059 us; speedup 1.0000x reference)
//
#include <hip/hip_runtime.h>

// GCN: 2x (GCNConv + ReLU) + FC.  N=100000, E=1600000, F: 128 -> 64 -> 64 -> 32. fp32.
//
// R15: mm2/fc fused into agg kernels (row-local). aggmm block owns 64 nodes;
// relu -> 64x64 bf16 LDS tile -> K=64 MFMA vs LDS W^T -> next table.
// R16-R18: aggmm gather restructures; 49 -> 42.7us (R18 = best, kept verbatim).
// R19/R19b: binA range-reservation partition; rescale folded into mm1. ->228.9
// R20/R21: EPB halving and aggmm unroll fast path both regressed; reverted.
// R22: banked best combo: 226.8us.  aggmm x2 = 86us; ~141us in
//      {zeroK,binA,sortB,mm1}+gaps, each <42.7us (invisible to top-5).
// R23: OVERLAP sortB with mm1 in one role-split dispatch (R15 pattern):
//  - mm1 only needs per-node degree, not the sorted CSR.  binA now also
//    maintains deg[node] (1 global atomicAdd/edge, L2-resident).
//  - sortmm dispatch: blocks 0..nb-1 = sortB (unchanged); blocks nb.. =
//    mm1 tile with dinv computed as rsqrtf(deg+1) in the epilogue
//    (bitwise-identical to sortB's dinv; dinv[] array NOT read -> no race).
//  - 391 barrier-heavy sort blocks interleave with 1563 memory/MFMA blocks
//    on the CUs: combined ~= max instead of sum; one dispatch+gap removed.
// Pipeline (5 dispatches): zero2 -> binA(+deg) -> sortmm -> aggmm(M=64) ->
//                          aggmm(M=32).

#define THREADS 256
#define THREADS_A 512
#define BIN_T 512
#define EPB 4096
#define BKT 256
#define CAP 8064
#define SORT_CAP 8192

typedef unsigned short ushort_t;
typedef __attribute__((ext_vector_type(8))) short short8;
typedef __attribute__((ext_vector_type(4))) float f32x4;
typedef __attribute__((ext_vector_type(2))) float f32x2;

__device__ __forceinline__ ushort_t f2bf(float f) {  // round-to-nearest-even
    unsigned u = __float_as_uint(f);
    u += 0x7FFFu + ((u >> 16) & 1u);
    return (ushort_t)(u >> 16);
}
__device__ __forceinline__ float bflo(unsigned v) { return __uint_as_float(v << 16); }
__device__ __forceinline__ float bfhi(unsigned v) { return __uint_as_float(v & 0xFFFF0000u); }

// ---- Kernel 0: zero cntg + deg (graph-capture-safe memset) -----------------

__global__ __launch_bounds__(BIN_T) void zero2_kernel(int* __restrict__ cntg, int nb,
                                                      int* __restrict__ deg, int N) {
    const int i = (int)(blockIdx.x * blockDim.x + threadIdx.x);
    if (i < nb) cntg[i] = 0;
    for (int j = i; j < N; j += (int)(gridDim.x * blockDim.x)) deg[j] = 0;
}

// ---- Kernel 1: binA - bucket count + range reservation + coalesced scatter -
// Also accumulates deg[node] (global atomics) for the overlapped mm1.

__global__ __launch_bounds__(BIN_T) void binA_kernel(const int* __restrict__ src,
                                                     const int* __restrict__ dst, int E,
                                                     int nb,
                                                     int* __restrict__ cntg,
                                                     int* __restrict__ deg,
                                                     unsigned* __restrict__ stagePad) {
    __shared__ unsigned ebuf[EPB];    // packed (d&255)<<17 | src, load order
    __shared__ unsigned ebuf2[EPB];   // bucket-sorted entries
    __shared__ unsigned eaddr[EPB];   // global address per sorted slot
    __shared__ ushort_t ebkt[EPB];    // bucket id per loaded entry
    __shared__ int cnt[BIN_T], cur[BIN_T], gb[BIN_T];
    const int t = threadIdx.x;
    const int e0 = blockIdx.x * EPB;
    const int n = min(EPB, E - e0);
    cnt[t] = 0;
    __syncthreads();
    for (int i = t; i < n; i += BIN_T) {
        const int d = dst[e0 + i];
        const int s = src[e0 + i];
        ebuf[i] = ((unsigned)(d & (BKT - 1)) << 17) | (unsigned)s;
        const int b = d >> 8;
        ebkt[i] = (ushort_t)b;
        atomicAdd(&cnt[b], 1);
        atomicAdd(&deg[d], 1);        // per-node degree for overlapped mm1
    }
    __syncthreads();
    // Inclusive scan of cnt in cur -> exclusive local offsets.
    const int v = cnt[t];
    cur[t] = v;
    __syncthreads();
    for (int off = 1; off < BIN_T; off <<= 1) {
        int u = (t >= off) ? cur[t - off] : 0;
        __syncthreads();
        cur[t] += u;
        __syncthreads();
    }
    const int excl = cur[t] - v;
    if (t < nb && v > 0) {
        const int resv = atomicAdd(&cntg[t], v);
        gb[t] = t * CAP + resv - excl;
    }
    __syncthreads();
    cur[t] = excl;
    __syncthreads();
    // Reorder into bucket-sorted LDS + compute final global addresses.
    for (int i = t; i < n; i += BIN_T) {
        const int b = (int)ebkt[i];
        const int p = atomicAdd(&cur[b], 1);
        ebuf2[p] = ebuf[i];
        eaddr[p] = (unsigned)(gb[b] + p);
    }
    __syncthreads();
    // Coalesced-run output (eaddr increments by 1 within each bucket run).
    for (int i = t; i < n; i += BIN_T)
        stagePad[eaddr[i]] = ebuf2[i];
}

// ---- Kernel 2: fused sortB (blocks < nb) + mm1 (blocks >= nb) --------------
// sortB: per-bucket counting sort + row/dinv, self-computed bucket prefix.
// mm1:   64-row MFMA tile, epilogue scales by rsqrtf(deg+1) (== dinv).

template <int K, int M>
__global__ __launch_bounds__(THREADS) void sortmm_kernel(const unsigned* __restrict__ stagePad,
                                                         const int* __restrict__ cntg,
                                                         int nb, int N,
                                                         int* __restrict__ row,
                                                         float* __restrict__ dinv,
                                                         unsigned* __restrict__ srt,
                                                         const float* __restrict__ Xf,
                                                         const float* __restrict__ W,
                                                         const int* __restrict__ deg,
                                                         ushort_t* __restrict__ Yv) {
    constexpr int XROW = K + 4;
    constexpr int XB = 64 * XROW * 4;          // 33792 B
    constexpr int WROW = K + 8;
    constexpr int WB = M * WROW * 2;           // 17408 B
    constexpr int CB = 64 * M * 4;             // 16384 B
    constexpr int MMB_ = (XB + WB > CB) ? (XB + WB) : CB;   // 51200 B
    constexpr int SB_ = SORT_CAP * 4 + 4 * BKT * 4;         // 36864 B
    constexpr int SMEM = (MMB_ > SB_) ? MMB_ : SB_;
    __shared__ __align__(16) char smem[SMEM];
    const int t = threadIdx.x;

    if ((int)blockIdx.x < nb) {
        // ---------------- sortB path ----------------
        unsigned* buf = (unsigned*)smem;
        int* cnt = (int*)(smem + SORT_CAP * 4);
        int* cur = cnt + BKT;
        int* scn = cur + BKT;
        int* red = scn + BKT;
        const int b = blockIdx.x;
        // Bucket prefix: bs = sum(cntg[0..b-1]) via strided loads + tree reduce.
        int part = 0;
        for (int j = t; j < b; j += THREADS) part += cntg[j];
        red[t] = part;
        __syncthreads();
#pragma unroll
        for (int off = THREADS / 2; off > 0; off >>= 1) {
            if (t < off) red[t] += red[t + off];
            __syncthreads();
        }
        const int bs = red[0];
        const int m = cntg[b];
        const unsigned* base = stagePad + (size_t)b * CAP;
        cnt[t] = 0;
        __syncthreads();
        for (int i = t; i < m; i += THREADS) {
            const unsigned v = base[i];
            buf[i] = v;
            atomicAdd(&cnt[v >> 17], 1);
        }
        __syncthreads();
        const int c = cnt[t];
        scn[t] = c;
        __syncthreads();
        for (int off = 1; off < BKT; off <<= 1) {
            int u = (t >= off) ? scn[t - off] : 0;
            __syncthreads();
            scn[t] += u;
            __syncthreads();
        }
        const int excl = scn[t] - c;
        cur[t] = excl;
        const int node = b * BKT + t;
        if (node < N) {
            row[node] = bs + excl;
            dinv[node] = rsqrtf((float)c + 1.0f);
        }
        __syncthreads();
        for (int i = t; i < m; i += THREADS) {
            const unsigned v = buf[i];
            const int pos = atomicAdd(&cur[v >> 17], 1);
            srt[bs + pos] = v & 0x1FFFFu;
        }
        return;
    }

    // ---------------- mm1 path ----------------
    const int row0 = ((int)blockIdx.x - nb) * 64;
    ushort_t* WsU = (ushort_t*)(smem + XB);
    for (int i = t; i < K * M; i += THREADS) {
        const int k = i / M, m = i % M;
        WsU[m * WROW + k] = f2bf(W[i]);
    }
    float* XsF = (float*)smem;
    for (int i = t; i < 64 * K / 4; i += THREADS) {
        const int r = i / (K / 4), kc = i % (K / 4);
        const unsigned gr = (unsigned)min(row0 + r, N - 1);
        *(float4*)(XsF + r * XROW + kc * 4) = *(const float4*)(Xf + (size_t)gr * K + kc * 4);
    }
    __syncthreads();

    const int w = t >> 6, lane = t & 63;
    const int m0 = w * 16, lm = lane & 15, q = lane >> 4;
    f32x4 acc[M / 16];
#pragma unroll
    for (int c = 0; c < M / 16; ++c) acc[c] = (f32x4)0.0f;

#pragma unroll
    for (int s = 0; s < K / 32; ++s) {
        const float* xr = (const float*)smem + (size_t)(m0 + lm) * XROW + s * 32 + q * 8;
        const float4 f0 = *(const float4*)xr;
        const float4 f1 = *(const float4*)(xr + 4);
        short8 a;
        a[0] = (short)f2bf(f0.x); a[1] = (short)f2bf(f0.y);
        a[2] = (short)f2bf(f0.z); a[3] = (short)f2bf(f0.w);
        a[4] = (short)f2bf(f1.x); a[5] = (short)f2bf(f1.y);
        a[6] = (short)f2bf(f1.z); a[7] = (short)f2bf(f1.w);
#pragma unroll
        for (int c = 0; c < M / 16; ++c) {
            const short8 b = *(const short8*)(WsU + (size_t)(c * 16 + lm) * WROW + s * 32 + q * 8);
            acc[c] = __builtin_amdgcn_mfma_f32_16x16x32_bf16(a, b, acc[c], 0, 0, 0);
        }
    }
    __syncthreads();
    float* Cs = (float*)smem;
#pragma unroll
    for (int c = 0; c < M / 16; ++c)
#pragma unroll
        for (int r = 0; r < 4; ++r)
            Cs[(size_t)(m0 + q * 4 + r) * M + c * 16 + lm] = acc[c][r];
    __syncthreads();

    for (int g = t; g < 64 * M / 4; g += THREADS) {
        const int r = g / (M / 4);
        const int gr = row0 + r;
        if (gr >= N) continue;
        float4 o = *(const float4*)(Cs + (size_t)g * 4);
        const float dv = rsqrtf((float)deg[gr] + 1.0f);   // == dinv[gr], no race
        o.x *= dv; o.y *= dv; o.z *= dv; o.w *= dv;
        const int col = (g % (M / 4)) * 4;
        ushort4 pk = {f2bf(o.x), f2bf(o.y), f2bf(o.z), f2bf(o.w)};
        *(ushort4*)(Yv + (size_t)gr * M + col) = pk;
    }
}

// ---- Fused aggregate + row-local MFMA matmul (R18 version, best measured) --
// Block owns 64 nodes; 8 waves, wave w handles nodes w*8..w*8+7 sequentially.
// Phase 1 (gather): 16 lanes/edge (dwordx2), 4 edges per wave-instr; chunk
// idx vectors prefetched one node ahead.  relu(dinv*(Hself+sum)+abias) ->
// bf16 LDS tile Rl[64][72u].
// Phase 2 (MFMA):  Y[64][M] = Rl @ W; wave = (row-strip w>>1, col-half w&1).
// MODE 1: Y *= dinv -> bf16 pair table.  MODE 2: Y += fbias -> fp32 out.

template <int M, int MODE>
__global__ __launch_bounds__(THREADS_A) void aggmm_kernel(const unsigned* __restrict__ srt,
                                                          const int* __restrict__ row,
                                                          const float* __restrict__ dinv,
                                                          const unsigned* __restrict__ H2,
                                                          const float* __restrict__ abias,
                                                          const float* __restrict__ W,
                                                          const float* __restrict__ fbias,
                                                          void* __restrict__ Yv,
                                                          int N, int E) {
    constexpr int K = 64;
    constexpr int RROW = 36;                 // relu-tile row stride in dwords (72 ushorts)
    constexpr int RB = 64 * RROW * 4;        // 9216 B
    constexpr int WROW = K + 8;              // 72 ushorts
    constexpr int WB = M * WROW * 2;
    constexpr int CB = 64 * M * 4;
    constexpr int SMEM = (RB + WB > CB) ? (RB + WB) : CB;
    __shared__ __align__(16) char smem[SMEM];
    const int t = threadIdx.x;
    const int w = t >> 6, lane = t & 63;
    const int row0 = blockIdx.x * 64;

    // Stage W^T bf16 (phase 1 doesn't read it; barrier below covers it).
    ushort_t* WsU = (ushort_t*)(smem + RB);
    for (int i = t; i < K * M; i += THREADS_A) {
        const int k = i / M, m = i % M;
        WsU[m * WROW + k] = f2bf(W[i]);
    }

    // Phase 1: gather+relu for this wave's 8 nodes.
    unsigned* Rl = (unsigned*)smem;
    const int col2 = lane & 15;              // dword-pair within 32-dword row
    const int slot = lane >> 4;              // edge slot 0..3
    const unsigned roff = (unsigned)(col2 * 2);
    const unsigned cap = (unsigned)(N - 1);
    const int node00 = row0 + w * 8;
    // Wave-invariant bias (hoisted off the per-node chain).
    const float4 bias4 = *(const float4*)(abias + col2 * 4);
    // Row/dinv prefetch: lanes 0..9 hold row[node00+lane] (E past the end).
    int rv;
    float dvv;
    {
        const int ridx = node00 + (int)lane;
        const bool okr = ridx < N;
        rv = okr ? row[ridx] : E;
        dvv = okr ? dinv[ridx] : 0.0f;
    }
    // Prefetch node-0 chunk-0 idx (16 lanes cooperative, broadcast pattern).
    int sc = __shfl(rv, 0, 64);
    int ec = __shfl(rv, 1, 64);
    unsigned idx0 = srt[sc + col2];
#pragma unroll 1
    for (int i = 0; i < 8; ++i) {
        const int node = node00 + i;
        if (node >= N) break;
        const int start = sc, end = ec;
        unsigned idx = idx0;
        if (i < 7) {  // prefetch next node's chunk-0 idx during this node
            sc = __shfl(rv, i + 1, 64);
            ec = __shfl(rv, i + 2, 64);
            idx0 = srt[sc + col2];
        }
        // Self-loop row, issued early (independent of gathers).
        const uint2 sv = *(const uint2*)(H2 + (((unsigned)node << 5) + roff));
        f32x2 a0 = {0.0f, 0.0f}, a1 = {0.0f, 0.0f};
        int base = start;
        while (base + 16 <= end) {
            unsigned idxn = 0;
            if (base + 16 < end)  // prefetch next chunk idx before the adds
                idxn = srt[base + 16 + col2];
#pragma unroll
            for (int g = 0; g < 4; ++g) {
                const unsigned r = (unsigned)__shfl((int)idx, g * 4 + slot, 64);
                const uint2 v = *(const uint2*)(H2 + ((r << 5) + roff));
                a0 += (f32x2){bflo(v.x), bfhi(v.x)};
                a1 += (f32x2){bflo(v.y), bfhi(v.y)};
            }
            base += 16;
            idx = idxn;
        }
        const int rem = end - base;
        if (rem > 0) {
#pragma unroll
            for (int g = 0; g < 4; ++g) {
                if (g * 4 >= rem) break;               // wave-uniform
                const int e = g * 4 + slot;
                unsigned r = (unsigned)__shfl((int)idx, e, 64) & 0x1FFFFu;
                r = min(r, cap);                       // garbage past end
                uint2 v = *(const uint2*)(H2 + ((r << 5) + roff));
                const bool ok = e < rem;
                v.x = ok ? v.x : 0u;
                v.y = ok ? v.y : 0u;
                a0 += (f32x2){bflo(v.x), bfhi(v.x)};
                a1 += (f32x2){bflo(v.y), bfhi(v.y)};
            }
        }
        // Reduce across the 4 edge slots (lanes 16 apart share col2).
        a0.x += __shfl_xor(a0.x, 16, 64);
        a0.y += __shfl_xor(a0.y, 16, 64);
        a1.x += __shfl_xor(a1.x, 16, 64);
        a1.y += __shfl_xor(a1.y, 16, 64);
        a0.x += __shfl_xor(a0.x, 32, 64);
        a0.y += __shfl_xor(a0.y, 32, 64);
        a1.x += __shfl_xor(a1.x, 32, 64);
        a1.y += __shfl_xor(a1.y, 32, 64);
        const float d = __shfl(dvv, i, 64);
        if (slot == 0) {
            const float o0 = fmaxf(fmaf(a0.x + bflo(sv.x), d, bias4.x), 0.0f);
            const float o1 = fmaxf(fmaf(a0.y + bfhi(sv.x), d, bias4.y), 0.0f);
            const float o2 = fmaxf(fmaf(a1.x + bflo(sv.y), d, bias4.z), 0.0f);
            const float o3 = fmaxf(fmaf(a1.y + bfhi(sv.y), d, bias4.w), 0.0f);
            uint2 pk;
            pk.x = ((unsigned)f2bf(o1) << 16) | (unsigned)f2bf(o0);
            pk.y = ((unsigned)f2bf(o3) << 16) | (unsigned)f2bf(o2);
            *(uint2*)(Rl + (size_t)(w * 8 + i) * RROW + col2 * 2) = pk;
        }
    }
    __syncthreads();

    // Phase 2: MFMA over the relu tile. Wave = (row-strip, col-half).
    constexpr int TW = M / 32;               // col tiles per wave (64->2, 32->1)
    const int m0 = (w >> 1) * 16, lm = lane & 15, q = lane >> 4;
    const int c0 = (w & 1) * TW;
    f32x4 acc[TW];
#pragma unroll
    for (int c = 0; c < TW; ++c) acc[c] = (f32x4)0.0f;
#pragma unroll
    for (int s = 0; s < K / 32; ++s) {
        const short8 a = *(const short8*)((const ushort_t*)Rl + (size_t)(m0 + lm) * 72 + s * 32 + q * 8);
#pragma unroll
        for (int c = 0; c < TW; ++c) {
            const short8 b = *(const short8*)(WsU + (size_t)((c0 + c) * 16 + lm) * WROW + s * 32 + q * 8);
            acc[c] = __builtin_amdgcn_mfma_f32_16x16x32_bf16(a, b, acc[c], 0, 0, 0);
        }
    }
    __syncthreads();   // Rl/Ws dead; reuse as C [64][M] f32
    float* Cs = (float*)smem;
#pragma unroll
    for (int c = 0; c < TW; ++c)
#pragma unroll
        for (int r = 0; r < 4; ++r)
            Cs[(size_t)(m0 + q * 4 + r) * M + (c0 + c) * 16 + lm] = acc[c][r];
    __syncthreads();

    for (int g = t; g < 64 * M / 4; g += THREADS_A) {
        const int r = g / (M / 4);
        const int gr = row0 + r;
        if (gr >= N) continue;
        float4 o = *(const float4*)(Cs + (size_t)g * 4);
        const int col = (g % (M / 4)) * 4;
        if (MODE == 1) {
            const float d = dinv[gr];
            o.x *= d; o.y *= d; o.z *= d; o.w *= d;
            ushort4 pk = {f2bf(o.x), f2bf(o.y), f2bf(o.z), f2bf(o.w)};
            *(ushort4*)((ushort_t*)Yv + (size_t)gr * M + col) = pk;
        } else {
            o.x += fbias[col]; o.y += fbias[col + 1];
            o.z += fbias[col + 2]; o.w += fbias[col + 3];
            *(float4*)((float*)Yv + (size_t)gr * M + col) = o;
        }
    }
}

// ---- Launch ----------------------------------------------------------------

extern "C" void kernel_launch(void* const* d_in, const int* in_sizes, int n_in,
                              void* d_out, int out_size, void* d_ws, size_t ws_size,
                              hipStream_t stream) {
    const float* x   = (const float*)d_in[0];
    const int*   ei  = (const int*)d_in[1];   // [2, E] int32
    const float* W1  = (const float*)d_in[3];
    const float* b1  = (const float*)d_in[4];
    const float* W2  = (const float*)d_in[5];
    const float* b2  = (const float*)d_in[6];
    const float* Wfc = (const float*)d_in[7];
    const float* bfc = (const float*)d_in[8];
    float* out = (float*)d_out;

    const int N = in_sizes[0] / 128;
    const int E = in_sizes[1] / 2;
    const int* src = ei;
    const int* dst = ei + E;

    const int nb   = (N + BKT - 1) / BKT;     // 391 buckets
    const int nblk = (E + EPB - 1) / EPB;     // 391 edge-chunks

    // Workspace (256 B-aligned slices).
    char* p = (char*)d_ws;
    auto alloc = [&](size_t bytes) { char* r = p; p += (bytes + 255) & ~(size_t)255; return r; };
    int*      cntg   = (int*)alloc((size_t)nb * 4);
    int*      deg    = (int*)alloc((size_t)N * 4);
    unsigned* srt    = (unsigned*)alloc((size_t)E * 4);
    int*      row    = (int*)alloc((size_t)N * 4);     // also absorbs agg tail over-reads
    float*    dinv   = (float*)alloc((size_t)N * 4);
    ushort_t* bufH   = (ushort_t*)alloc((size_t)N * 64 * 2);   // H1 table (bf16, *dinv)
    ushort_t* bufR   = (ushort_t*)alloc((size_t)N * 64 * 2);   // H2 table; doubles as stagePad
    unsigned* stagePad = (unsigned*)bufR;     // nb*CAP*4 = 12.61 MB <= 12.8 MB, dead before aggmm-1

    const int mmB = (N + 63) / 64;
    const int zB  = (N + BIN_T - 1) / BIN_T;

    // 0) zero cntg + deg (kernel, not hipMemsetAsync: graph-capture-safe).
    zero2_kernel<<<zB, BIN_T, 0, stream>>>(cntg, nb, deg, N);
    // 1) bucket-bin edges (range reservation, coalesced scatter) + deg counts.
    binA_kernel<<<nblk, BIN_T, 0, stream>>>(src, dst, E, nb, cntg, deg, stagePad);
    // 2) fused: per-bucket counting sort (blocks<nb) || mm1 MFMA (blocks>=nb).
    sortmm_kernel<128, 64><<<nb + mmB, THREADS, 0, stream>>>(
        stagePad, cntg, nb, N, row, dinv, srt, x, W1, deg, bufH);
    // 3) agg layer1 + mm2 fused -> H2 table (bf16, *dinv).
    aggmm_kernel<64, 1><<<mmB, THREADS_A, 0, stream>>>(
        srt, row, dinv, (const unsigned*)bufH, b1, W2, nullptr, bufR, N, E);
    // 4) agg layer2 + fc fused -> fp32 out (+bfc).
    aggmm_kernel<32, 2><<<mmB, THREADS_A, 0, stream>>>(
        srt, row, dinv, (const unsigned*)bufR, b2, Wfc, bfc, out, N, E);
}

// Round 10
// 232.938 us; speedup vs baseline: 1.1894x; 1.1894x over previous
//
#include <hip/hip_runtime.h>

// GCN: 2x (GCNConv + ReLU) + FC.  N=100000, E=1600000, F: 128 -> 64 -> 64 -> 32. fp32.
//
// R15: mm2/fc fused into agg kernels (row-local). aggmm block owns 64 nodes;
// relu -> 64x64 bf16 LDS tile -> K=64 MFMA vs LDS W^T -> next table.
// R16-R18: aggmm gather restructures; 49 -> 42.7us (R18 = best, kept verbatim).
// R19/R19b: binA range-reservation partition; rescale folded into mm1. ->228.9
// R20/R21: EPB halving and aggmm unroll fast path both regressed; reverted.
// R22: banked best combo: 226.8us.
// R23: deg[] via 1.6M random device atomics in binA REGRESSED HARD: binA
//   41->75us (VALU 1.4%, occ 26% = pure coherence-point stall, ~25ns/atomic).
//   Also measured: binA WRITE_SIZE 59.6MB (9x write amplification).
// R24: keep the sort||mm1 overlap, drop the atomics: mm1 blocks self-compute
//   their 64 node degrees by scanning their bucket's staged entries (avg
//   16/thread, L2-resident, coalesced) into a 64-entry LDS histogram.  Sort
//   path still writes dinv (no reader in this dispatch -> no race); mm1 uses
//   rsqrtf(cnt+1) locally (bitwise-identical).  binA/aggmm = R22 verbatim.
// Pipeline (5 dispatches): zeroK -> binA -> sortmm(sort||mm1) ->
//                          aggmm(M=64,*dinv,bf16) -> aggmm(M=32,+bias,f32).

#define THREADS 256
#define THREADS_A 512
#define BIN_T 512
#define EPB 4096
#define BKT 256
#define CAP 8064
#define SORT_CAP 8192

typedef unsigned short ushort_t;
typedef __attribute__((ext_vector_type(8))) short short8;
typedef __attribute__((ext_vector_type(4))) float f32x4;
typedef __attribute__((ext_vector_type(2))) float f32x2;

__device__ __forceinline__ ushort_t f2bf(float f) {  // round-to-nearest-even
    unsigned u = __float_as_uint(f);
    u += 0x7FFFu + ((u >> 16) & 1u);
    return (ushort_t)(u >> 16);
}
__device__ __forceinline__ float bflo(unsigned v) { return __uint_as_float(v << 16); }
__device__ __forceinline__ float bfhi(unsigned v) { return __uint_as_float(v & 0xFFFF0000u); }

// ---- Kernel 0: zero the bucket counters (graph-capture-safe memset) --------

__global__ __launch_bounds__(BIN_T) void zeroK_kernel(int* __restrict__ p, int n) {
    const int i = (int)threadIdx.x;
    if (i < n) p[i] = 0;
}

// ---- Kernel 1: binA - bucket count + range reservation + coalesced scatter -

__global__ __launch_bounds__(BIN_T) void binA_kernel(const int* __restrict__ src,
                                                     const int* __restrict__ dst, int E,
                                                     int nb,
                                                     int* __restrict__ cntg,
                                                     unsigned* __restrict__ stagePad) {
    __shared__ unsigned ebuf[EPB];    // packed (d&255)<<17 | src, load order
    __shared__ unsigned ebuf2[EPB];   // bucket-sorted entries
    __shared__ unsigned eaddr[EPB];   // global address per sorted slot
    __shared__ ushort_t ebkt[EPB];    // bucket id per loaded entry
    __shared__ int cnt[BIN_T], cur[BIN_T], gb[BIN_T];
    const int t = threadIdx.x;
    const int e0 = blockIdx.x * EPB;
    const int n = min(EPB, E - e0);
    cnt[t] = 0;
    __syncthreads();
    for (int i = t; i < n; i += BIN_T) {
        const int d = dst[e0 + i];
        const int s = src[e0 + i];
        ebuf[i] = ((unsigned)(d & (BKT - 1)) << 17) | (unsigned)s;
        const int b = d >> 8;
        ebkt[i] = (ushort_t)b;
        atomicAdd(&cnt[b], 1);
    }
    __syncthreads();
    // Inclusive scan of cnt in cur -> exclusive local offsets.
    const int v = cnt[t];
    cur[t] = v;
    __syncthreads();
    for (int off = 1; off < BIN_T; off <<= 1) {
        int u = (t >= off) ? cur[t - off] : 0;
        __syncthreads();
        cur[t] += u;
        __syncthreads();
    }
    const int excl = cur[t] - v;
    if (t < nb && v > 0) {
        const int resv = atomicAdd(&cntg[t], v);
        gb[t] = t * CAP + resv - excl;
    }
    __syncthreads();
    cur[t] = excl;
    __syncthreads();
    // Reorder into bucket-sorted LDS + compute final global addresses.
    for (int i = t; i < n; i += BIN_T) {
        const int b = (int)ebkt[i];
        const int p = atomicAdd(&cur[b], 1);
        ebuf2[p] = ebuf[i];
        eaddr[p] = (unsigned)(gb[b] + p);
    }
    __syncthreads();
    // Coalesced-run output (eaddr increments by 1 within each bucket run).
    for (int i = t; i < n; i += BIN_T)
        stagePad[eaddr[i]] = ebuf2[i];
}

// ---- Kernel 2: fused sortB (blocks < nb) + mm1 (blocks >= nb) --------------
// sortB: per-bucket counting sort + row/dinv, self-computed bucket prefix.
// mm1:   64-row MFMA tile; degrees self-counted from the block's bucket
//        staging (64-entry LDS histogram); epilogue scales by rsqrtf(cnt+1).

template <int K, int M>
__global__ __launch_bounds__(THREADS) void sortmm_kernel(const unsigned* __restrict__ stagePad,
                                                         const int* __restrict__ cntg,
                                                         int nb, int N,
                                                         int* __restrict__ row,
                                                         float* __restrict__ dinv,
                                                         unsigned* __restrict__ srt,
                                                         const float* __restrict__ Xf,
                                                         const float* __restrict__ W,
                                                         ushort_t* __restrict__ Yv) {
    constexpr int XROW = K + 4;
    constexpr int XB = 64 * XROW * 4;          // 33792 B
    constexpr int WROW = K + 8;
    constexpr int WB = M * WROW * 2;           // 17408 B
    constexpr int CB = 64 * M * 4;             // 16384 B (reuses smem[0..) )
    constexpr int MMB_ = XB + WB + 64 * 4;     // X + W + cnt64 tail = 51456 B
    constexpr int SB_ = SORT_CAP * 4 + 4 * BKT * 4;         // 36864 B
    constexpr int SMEM = (MMB_ > SB_) ? ((MMB_ > CB) ? MMB_ : CB) : SB_;
    __shared__ __align__(16) char smem[SMEM];
    const int t = threadIdx.x;

    if ((int)blockIdx.x < nb) {
        // ---------------- sortB path (R22 verbatim) ----------------
        unsigned* buf = (unsigned*)smem;
        int* cnt = (int*)(smem + SORT_CAP * 4);
        int* cur = cnt + BKT;
        int* scn = cur + BKT;
        int* red = scn + BKT;
        const int b = blockIdx.x;
        // Bucket prefix: bs = sum(cntg[0..b-1]) via strided loads + tree reduce.
        int part = 0;
        for (int j = t; j < b; j += THREADS) part += cntg[j];
        red[t] = part;
        __syncthreads();
#pragma unroll
        for (int off = THREADS / 2; off > 0; off >>= 1) {
            if (t < off) red[t] += red[t + off];
            __syncthreads();
        }
        const int bs = red[0];
        const int m = cntg[b];
        const unsigned* base = stagePad + (size_t)b * CAP;
        cnt[t] = 0;
        __syncthreads();
        for (int i = t; i < m; i += THREADS) {
            const unsigned v = base[i];
            buf[i] = v;
            atomicAdd(&cnt[v >> 17], 1);
        }
        __syncthreads();
        const int c = cnt[t];
        scn[t] = c;
        __syncthreads();
        for (int off = 1; off < BKT; off <<= 1) {
            int u = (t >= off) ? scn[t - off] : 0;
            __syncthreads();
            scn[t] += u;
            __syncthreads();
        }
        const int excl = scn[t] - c;
        cur[t] = excl;
        const int node = b * BKT + t;
        if (node < N) {
            row[node] = bs + excl;
            dinv[node] = rsqrtf((float)c + 1.0f);   // not read in this dispatch
        }
        __syncthreads();
        for (int i = t; i < m; i += THREADS) {
            const unsigned v = buf[i];
            const int pos = atomicAdd(&cur[v >> 17], 1);
            srt[bs + pos] = v & 0x1FFFFu;
        }
        return;
    }

    // ---------------- mm1 path ----------------
    const int row0 = ((int)blockIdx.x - nb) * 64;
    int* cnt64 = (int*)(smem + XB + WB);       // survives Cs reuse (Cs = 16KB at smem[0])
    if (t < 64) cnt64[t] = 0;
    ushort_t* WsU = (ushort_t*)(smem + XB);
    for (int i = t; i < K * M; i += THREADS) {
        const int k = i / M, m = i % M;
        WsU[m * WROW + k] = f2bf(W[i]);
    }
    float* XsF = (float*)smem;
    for (int i = t; i < 64 * K / 4; i += THREADS) {
        const int r = i / (K / 4), kc = i % (K / 4);
        const unsigned gr = (unsigned)min(row0 + r, N - 1);
        *(float4*)(XsF + r * XROW + kc * 4) = *(const float4*)(Xf + (size_t)gr * K + kc * 4);
    }
    // Degree self-count: scan this block's bucket staging (L2-resident).
    {
        const int b = row0 >> 8;               // bucket holding these 64 nodes
        const int lo = row0 & (BKT - 1);       // local offset of node row0
        const int m = cntg[b];
        const unsigned* base = stagePad + (size_t)b * CAP;
        for (int i = t; i < m; i += THREADS) {
            const int dl = (int)(base[i] >> 17) - lo;
            if ((unsigned)dl < 64u) atomicAdd(&cnt64[dl], 1);
        }
    }
    __syncthreads();

    const int w = t >> 6, lane = t & 63;
    const int m0 = w * 16, lm = lane & 15, q = lane >> 4;
    f32x4 acc[M / 16];
#pragma unroll
    for (int c = 0; c < M / 16; ++c) acc[c] = (f32x4)0.0f;

#pragma unroll
    for (int s = 0; s < K / 32; ++s) {
        const float* xr = (const float*)smem + (size_t)(m0 + lm) * XROW + s * 32 + q * 8;
        const float4 f0 = *(const float4*)xr;
        const float4 f1 = *(const float4*)(xr + 4);
        short8 a;
        a[0] = (short)f2bf(f0.x); a[1] = (short)f2bf(f0.y);
        a[2] = (short)f2bf(f0.z); a[3] = (short)f2bf(f0.w);
        a[4] = (short)f2bf(f1.x); a[5] = (short)f2bf(f1.y);
        a[6] = (short)f2bf(f1.z); a[7] = (short)f2bf(f1.w);
#pragma unroll
        for (int c = 0; c < M / 16; ++c) {
            const short8 b = *(const short8*)(WsU + (size_t)(c * 16 + lm) * WROW + s * 32 + q * 8);
            acc[c] = __builtin_amdgcn_mfma_f32_16x16x32_bf16(a, b, acc[c], 0, 0, 0);
        }
    }
    __syncthreads();
    float* Cs = (float*)smem;                   // 16KB, below cnt64 (51200)
#pragma unroll
    for (int c = 0; c < M / 16; ++c)
#pragma unroll
        for (int r = 0; r < 4; ++r)
            Cs[(size_t)(m0 + q * 4 + r) * M + c * 16 + lm] = acc[c][r];
    __syncthreads();

    for (int g = t; g < 64 * M / 4; g += THREADS) {
        const int r = g / (M / 4);
        const int gr = row0 + r;
        if (gr >= N) continue;
        float4 o = *(const float4*)(Cs + (size_t)g * 4);
        const float dv = rsqrtf((float)cnt64[r] + 1.0f);   // == dinv[gr]
        o.x *= dv; o.y *= dv; o.z *= dv; o.w *= dv;
        const int col = (g % (M / 4)) * 4;
        ushort4 pk = {f2bf(o.x), f2bf(o.y), f2bf(o.z), f2bf(o.w)};
        *(ushort4*)(Yv + (size_t)gr * M + col) = pk;
    }
}

// ---- Fused aggregate + row-local MFMA matmul (R18 version, best measured) --
// Block owns 64 nodes; 8 waves, wave w handles nodes w*8..w*8+7 sequentially.
// Phase 1 (gather): 16 lanes/edge (dwordx2), 4 edges per wave-instr; chunk
// idx vectors prefetched one node ahead.  relu(dinv*(Hself+sum)+abias) ->
// bf16 LDS tile Rl[64][72u].
// Phase 2 (MFMA):  Y[64][M] = Rl @ W; wave = (row-strip w>>1, col-half w&1).
// MODE 1: Y *= dinv -> bf16 pair table.  MODE 2: Y += fbias -> fp32 out.

template <int M, int MODE>
__global__ __launch_bounds__(THREADS_A) void aggmm_kernel(const unsigned* __restrict__ srt,
                                                          const int* __restrict__ row,
                                                          const float* __restrict__ dinv,
                                                          const unsigned* __restrict__ H2,
                                                          const float* __restrict__ abias,
                                                          const float* __restrict__ W,
                                                          const float* __restrict__ fbias,
                                                          void* __restrict__ Yv,
                                                          int N, int E) {
    constexpr int K = 64;
    constexpr int RROW = 36;                 // relu-tile row stride in dwords (72 ushorts)
    constexpr int RB = 64 * RROW * 4;        // 9216 B
    constexpr int WROW = K + 8;              // 72 ushorts
    constexpr int WB = M * WROW * 2;
    constexpr int CB = 64 * M * 4;
    constexpr int SMEM = (RB + WB > CB) ? (RB + WB) : CB;
    __shared__ __align__(16) char smem[SMEM];
    const int t = threadIdx.x;
    const int w = t >> 6, lane = t & 63;
    const int row0 = blockIdx.x * 64;

    // Stage W^T bf16 (phase 1 doesn't read it; barrier below covers it).
    ushort_t* WsU = (ushort_t*)(smem + RB);
    for (int i = t; i < K * M; i += THREADS_A) {
        const int k = i / M, m = i % M;
        WsU[m * WROW + k] = f2bf(W[i]);
    }

    // Phase 1: gather+relu for this wave's 8 nodes.
    unsigned* Rl = (unsigned*)smem;
    const int col2 = lane & 15;              // dword-pair within 32-dword row
    const int slot = lane >> 4;              // edge slot 0..3
    const unsigned roff = (unsigned)(col2 * 2);
    const unsigned cap = (unsigned)(N - 1);
    const int node00 = row0 + w * 8;
    // Wave-invariant bias (hoisted off the per-node chain).
    const float4 bias4 = *(const float4*)(abias + col2 * 4);
    // Row/dinv prefetch: lanes 0..9 hold row[node00+lane] (E past the end).
    int rv;
    float dvv;
    {
        const int ridx = node00 + (int)lane;
        const bool okr = ridx < N;
        rv = okr ? row[ridx] : E;
        dvv = okr ? dinv[ridx] : 0.0f;
    }
    // Prefetch node-0 chunk-0 idx (16 lanes cooperative, broadcast pattern).
    int sc = __shfl(rv, 0, 64);
    int ec = __shfl(rv, 1, 64);
    unsigned idx0 = srt[sc + col2];
#pragma unroll 1
    for (int i = 0; i < 8; ++i) {
        const int node = node00 + i;
        if (node >= N) break;
        const int start = sc, end = ec;
        unsigned idx = idx0;
        if (i < 7) {  // prefetch next node's chunk-0 idx during this node
            sc = __shfl(rv, i + 1, 64);
            ec = __shfl(rv, i + 2, 64);
            idx0 = srt[sc + col2];
        }
        // Self-loop row, issued early (independent of gathers).
        const uint2 sv = *(const uint2*)(H2 + (((unsigned)node << 5) + roff));
        f32x2 a0 = {0.0f, 0.0f}, a1 = {0.0f, 0.0f};
        int base = start;
        while (base + 16 <= end) {
            unsigned idxn = 0;
            if (base + 16 < end)  // prefetch next chunk idx before the adds
                idxn = srt[base + 16 + col2];
#pragma unroll
            for (int g = 0; g < 4; ++g) {
                const unsigned r = (unsigned)__shfl((int)idx, g * 4 + slot, 64);
                const uint2 v = *(const uint2*)(H2 + ((r << 5) + roff));
                a0 += (f32x2){bflo(v.x), bfhi(v.x)};
                a1 += (f32x2){bflo(v.y), bfhi(v.y)};
            }
            base += 16;
            idx = idxn;
        }
        const int rem = end - base;
        if (rem > 0) {
#pragma unroll
            for (int g = 0; g < 4; ++g) {
                if (g * 4 >= rem) break;               // wave-uniform
                const int e = g * 4 + slot;
                unsigned r = (unsigned)__shfl((int)idx, e, 64) & 0x1FFFFu;
                r = min(r, cap);                       // garbage past end
                uint2 v = *(const uint2*)(H2 + ((r << 5) + roff));
                const bool ok = e < rem;
                v.x = ok ? v.x : 0u;
                v.y = ok ? v.y : 0u;
                a0 += (f32x2){bflo(v.x), bfhi(v.x)};
                a1 += (f32x2){bflo(v.y), bfhi(v.y)};
            }
        }
        // Reduce across the 4 edge slots (lanes 16 apart share col2).
        a0.x += __shfl_xor(a0.x, 16, 64);
        a0.y += __shfl_xor(a0.y, 16, 64);
        a1.x += __shfl_xor(a1.x, 16, 64);
        a1.y += __shfl_xor(a1.y, 16, 64);
        a0.x += __shfl_xor(a0.x, 32, 64);
        a0.y += __shfl_xor(a0.y, 32, 64);
        a1.x += __shfl_xor(a1.x, 32, 64);
        a1.y += __shfl_xor(a1.y, 32, 64);
        const float d = __shfl(dvv, i, 64);
        if (slot == 0) {
            const float o0 = fmaxf(fmaf(a0.x + bflo(sv.x), d, bias4.x), 0.0f);
            const float o1 = fmaxf(fmaf(a0.y + bfhi(sv.x), d, bias4.y), 0.0f);
            const float o2 = fmaxf(fmaf(a1.x + bflo(sv.y), d, bias4.z), 0.0f);
            const float o3 = fmaxf(fmaf(a1.y + bfhi(sv.y), d, bias4.w), 0.0f);
            uint2 pk;
            pk.x = ((unsigned)f2bf(o1) << 16) | (unsigned)f2bf(o0);
            pk.y = ((unsigned)f2bf(o3) << 16) | (unsigned)f2bf(o2);
            *(uint2*)(Rl + (size_t)(w * 8 + i) * RROW + col2 * 2) = pk;
        }
    }
    __syncthreads();

    // Phase 2: MFMA over the relu tile. Wave = (row-strip, col-half).
    constexpr int TW = M / 32;               // col tiles per wave (64->2, 32->1)
    const int m0 = (w >> 1) * 16, lm = lane & 15, q = lane >> 4;
    const int c0 = (w & 1) * TW;
    f32x4 acc[TW];
#pragma unroll
    for (int c = 0; c < TW; ++c) acc[c] = (f32x4)0.0f;
#pragma unroll
    for (int s = 0; s < K / 32; ++s) {
        const short8 a = *(const short8*)((const ushort_t*)Rl + (size_t)(m0 + lm) * 72 + s * 32 + q * 8);
#pragma unroll
        for (int c = 0; c < TW; ++c) {
            const short8 b = *(const short8*)(WsU + (size_t)((c0 + c) * 16 + lm) * WROW + s * 32 + q * 8);
            acc[c] = __builtin_amdgcn_mfma_f32_16x16x32_bf16(a, b, acc[c], 0, 0, 0);
        }
    }
    __syncthreads();   // Rl/Ws dead; reuse as C [64][M] f32
    float* Cs = (float*)smem;
#pragma unroll
    for (int c = 0; c < TW; ++c)
#pragma unroll
        for (int r = 0; r < 4; ++r)
            Cs[(size_t)(m0 + q * 4 + r) * M + (c0 + c) * 16 + lm] = acc[c][r];
    __syncthreads();

    for (int g = t; g < 64 * M / 4; g += THREADS_A) {
        const int r = g / (M / 4);
        const int gr = row0 + r;
        if (gr >= N) continue;
        float4 o = *(const float4*)(Cs + (size_t)g * 4);
        const int col = (g % (M / 4)) * 4;
        if (MODE == 1) {
            const float d = dinv[gr];
            o.x *= d; o.y *= d; o.z *= d; o.w *= d;
            ushort4 pk = {f2bf(o.x), f2bf(o.y), f2bf(o.z), f2bf(o.w)};
            *(ushort4*)((ushort_t*)Yv + (size_t)gr * M + col) = pk;
        } else {
            o.x += fbias[col]; o.y += fbias[col + 1];
            o.z += fbias[col + 2]; o.w += fbias[col + 3];
            *(float4*)((float*)Yv + (size_t)gr * M + col) = o;
        }
    }
}

// ---- Launch ----------------------------------------------------------------

extern "C" void kernel_launch(void* const* d_in, const int* in_sizes, int n_in,
                              void* d_out, int out_size, void* d_ws, size_t ws_size,
                              hipStream_t stream) {
    const float* x   = (const float*)d_in[0];
    const int*   ei  = (const int*)d_in[1];   // [2, E] int32
    const float* W1  = (const float*)d_in[3];
    const float* b1  = (const float*)d_in[4];
    const float* W2  = (const float*)d_in[5];
    const float* b2  = (const float*)d_in[6];
    const float* Wfc = (const float*)d_in[7];
    const float* bfc = (const float*)d_in[8];
    float* out = (float*)d_out;

    const int N = in_sizes[0] / 128;
    const int E = in_sizes[1] / 2;
    const int* src = ei;
    const int* dst = ei + E;

    const int nb   = (N + BKT - 1) / BKT;     // 391 buckets
    const int nblk = (E + EPB - 1) / EPB;     // 391 edge-chunks

    // Workspace (256 B-aligned slices).
    char* p = (char*)d_ws;
    auto alloc = [&](size_t bytes) { char* r = p; p += (bytes + 255) & ~(size_t)255; return r; };
    int*      cntg   = (int*)alloc((size_t)nb * 4);
    unsigned* srt    = (unsigned*)alloc((size_t)E * 4);
    int*      row    = (int*)alloc((size_t)N * 4);     // also absorbs agg tail over-reads
    float*    dinv   = (float*)alloc((size_t)N * 4);
    ushort_t* bufH   = (ushort_t*)alloc((size_t)N * 64 * 2);   // H1 table (bf16, *dinv)
    ushort_t* bufR   = (ushort_t*)alloc((size_t)N * 64 * 2);   // H2 table; doubles as stagePad
    unsigned* stagePad = (unsigned*)bufR;     // nb*CAP*4 = 12.61 MB <= 12.8 MB, dead before aggmm-1

    const int mmB = (N + 63) / 64;

    // 0) zero bucket counters (kernel, not hipMemsetAsync: graph-capture-safe).
    zeroK_kernel<<<1, BIN_T, 0, stream>>>(cntg, nb);
    // 1) bucket-bin edges with atomic range reservation + coalesced scatter.
    binA_kernel<<<nblk, BIN_T, 0, stream>>>(src, dst, E, nb, cntg, stagePad);
    // 2) fused: per-bucket counting sort (blocks<nb) || mm1 MFMA (blocks>=nb,
    //    degrees self-counted from bucket staging).
    sortmm_kernel<128, 64><<<nb + mmB, THREADS, 0, stream>>>(
        stagePad, cntg, nb, N, row, dinv, srt, x, W1, bufH);
    // 3) agg layer1 + mm2 fused -> H2 table (bf16, *dinv).
    aggmm_kernel<64, 1><<<mmB, THREADS_A, 0, stream>>>(
        srt, row, dinv, (const unsigned*)bufH, b1, W2, nullptr, bufR, N, E);
    // 4) agg layer2 + fc fused -> fp32 out (+bfc).
    aggmm_kernel<32, 2><<<mmB, THREADS_A, 0, stream>>>(
        srt, row, dinv, (const unsigned*)bufR, b2, Wfc, bfc, out, N, E);
}

// Round 11
// 226.556 us; speedup vs baseline: 1.2229x; 1.0282x over previous
//
#include <hip/hip_runtime.h>

// GCN: 2x (GCNConv + ReLU) + FC.  N=100000, E=1600000, F: 128 -> 64 -> 64 -> 32. fp32.
//
// R15: mm2/fc fused into agg kernels (row-local). aggmm block owns 64 nodes.
// R16-R18: aggmm gather restructures; 49 -> 42.7us (R18 best, kept verbatim).
// R19/R19b: binA range-reservation partition; dinv folded into mm1. -> 228.9
// R20/R21: EPB halving, aggmm unroll fast path: both regressed; reverted.
// R22: banked best combo: 226.8us.
// R23: per-edge global deg atomics: binA 40->75us (coherence stall). Reverted.
// R24: sort||mm1 fusion + LDS degree scan: 64-way same-address LDS atomic
//   serialization (bank-conflict 2.4M, occ 24.6%) => fusion gained nothing.
// R25: overlap TRULY independent paths: binmm = binA (blocks<nblk) || mm1
//   UNSCALED (blocks>=nblk, 512-thr).  mm1 reads only X/W1; dinv rescale of
//   H1 moves back into sortB (R15 mechanism; bufH mostly L2-resident).
//   binA slimmed: eaddr dropped (re-read dst for bucket in reorder; output
//   addr = gb[ebkt2[i]]+i) -> LDS 47KB; fused kernel 51.2KB -> 3 blocks/CU.
// Pipeline (5): zeroK -> binmm -> sortB(+H1 rescale) -> aggmm64 -> aggmm32.

#define THREADS 256
#define THREADS_A 512
#define BIN_T 512
#define EPB 4096
#define BKT 256
#define CAP 8064
#define SORT_CAP 8192

typedef unsigned short ushort_t;
typedef __attribute__((ext_vector_type(8))) short short8;
typedef __attribute__((ext_vector_type(4))) float f32x4;
typedef __attribute__((ext_vector_type(2))) float f32x2;

__device__ __forceinline__ ushort_t f2bf(float f) {  // round-to-nearest-even
    unsigned u = __float_as_uint(f);
    u += 0x7FFFu + ((u >> 16) & 1u);
    return (ushort_t)(u >> 16);
}
__device__ __forceinline__ float bflo(unsigned v) { return __uint_as_float(v << 16); }
__device__ __forceinline__ float bfhi(unsigned v) { return __uint_as_float(v & 0xFFFF0000u); }

// ---- Kernel 0: zero the bucket counters (graph-capture-safe memset) --------

__global__ __launch_bounds__(BIN_T) void zeroK_kernel(int* __restrict__ p, int n) {
    const int i = (int)threadIdx.x;
    if (i < n) p[i] = 0;
}

// ---- Kernel 1: binmm - role-split binA (blocks<nblk) || mm1 (blocks>=nblk) -
// binA: bucket count + range reservation + coalesced scatter (47KB LDS).
// mm1:  64-row MFMA tile, UNSCALED bf16 out (8 waves; no partition inputs).

template <int K, int M>
__global__ __launch_bounds__(THREADS_A) void binmm_kernel(const int* __restrict__ src,
                                                          const int* __restrict__ dst, int E,
                                                          int nb, int nblk,
                                                          int* __restrict__ cntg,
                                                          unsigned* __restrict__ stagePad,
                                                          const float* __restrict__ Xf,
                                                          const float* __restrict__ W,
                                                          ushort_t* __restrict__ Yv, int N) {
    constexpr int XROW = K + 4;
    constexpr int XB = 64 * XROW * 4;          // 33792 B
    constexpr int WROW = K + 8;
    constexpr int WB = M * WROW * 2;           // 17408 B -> mm1 = 51200 B
    constexpr int BA_ = EPB * 4 * 2 + EPB * 2 + BIN_T * 4 * 3;  // 47104 B
    constexpr int SMEM = (XB + WB > BA_) ? (XB + WB) : BA_;
    __shared__ __align__(16) char smem[SMEM];
    const int t = threadIdx.x;

    if ((int)blockIdx.x < nblk) {
        // ---------------- binA path ----------------
        unsigned* ebuf  = (unsigned*)smem;                 // 16384 B
        unsigned* ebuf2 = (unsigned*)(smem + EPB * 4);     // 16384 B
        ushort_t* ebkt2 = (ushort_t*)(smem + EPB * 8);     //  8192 B
        int* cnt = (int*)(smem + EPB * 8 + EPB * 2);       //  2048 B
        int* cur = cnt + BIN_T;
        int* gb  = cur + BIN_T;
        const int e0 = blockIdx.x * EPB;
        const int n = min(EPB, E - e0);
        cnt[t] = 0;
        __syncthreads();
        for (int i = t; i < n; i += BIN_T) {
            const int d = dst[e0 + i];
            const int s = src[e0 + i];
            ebuf[i] = ((unsigned)(d & (BKT - 1)) << 17) | (unsigned)s;
            atomicAdd(&cnt[d >> 8], 1);
        }
        __syncthreads();
        // Inclusive scan of cnt in cur -> exclusive local offsets.
        const int v = cnt[t];
        cur[t] = v;
        __syncthreads();
        for (int off = 1; off < BIN_T; off <<= 1) {
            int u = (t >= off) ? cur[t - off] : 0;
            __syncthreads();
            cur[t] += u;
            __syncthreads();
        }
        const int excl = cur[t] - v;
        if (t < nb && v > 0) {
            const int resv = atomicAdd(&cntg[t], v);
            gb[t] = t * CAP + resv - excl;
        }
        __syncthreads();
        cur[t] = excl;
        __syncthreads();
        // Reorder into bucket-sorted LDS (bucket recomputed from dst re-read).
        for (int i = t; i < n; i += BIN_T) {
            const int b = dst[e0 + i] >> 8;
            const int p = atomicAdd(&cur[b], 1);
            ebuf2[p] = ebuf[i];
            ebkt2[p] = (ushort_t)b;
        }
        __syncthreads();
        // Coalesced-run output (address increments by 1 within a bucket run).
        for (int i = t; i < n; i += BIN_T)
            stagePad[gb[(int)ebkt2[i]] + i] = ebuf2[i];
        return;
    }

    // ---------------- mm1 path (unscaled; 8 waves) ----------------
    const int row0 = ((int)blockIdx.x - nblk) * 64;
    ushort_t* WsU = (ushort_t*)(smem + XB);
    for (int i = t; i < K * M; i += THREADS_A) {
        const int k = i / M, m = i % M;
        WsU[m * WROW + k] = f2bf(W[i]);
    }
    float* XsF = (float*)smem;
    for (int i = t; i < 64 * K / 4; i += THREADS_A) {
        const int r = i / (K / 4), kc = i % (K / 4);
        const unsigned gr = (unsigned)min(row0 + r, N - 1);
        *(float4*)(XsF + r * XROW + kc * 4) = *(const float4*)(Xf + (size_t)gr * K + kc * 4);
    }
    __syncthreads();

    const int w = t >> 6, lane = t & 63;
    const int m0 = (w >> 1) * 16, lm = lane & 15, q = lane >> 4;
    const int c0 = (w & 1) * (M / 32);          // 2 col-tiles per wave (M=64)
    f32x4 acc[M / 32];
#pragma unroll
    for (int c = 0; c < M / 32; ++c) acc[c] = (f32x4)0.0f;

#pragma unroll
    for (int s = 0; s < K / 32; ++s) {
        const float* xr = (const float*)smem + (size_t)(m0 + lm) * XROW + s * 32 + q * 8;
        const float4 f0 = *(const float4*)xr;
        const float4 f1 = *(const float4*)(xr + 4);
        short8 a;
        a[0] = (short)f2bf(f0.x); a[1] = (short)f2bf(f0.y);
        a[2] = (short)f2bf(f0.z); a[3] = (short)f2bf(f0.w);
        a[4] = (short)f2bf(f1.x); a[5] = (short)f2bf(f1.y);
        a[6] = (short)f2bf(f1.z); a[7] = (short)f2bf(f1.w);
#pragma unroll
        for (int c = 0; c < M / 32; ++c) {
            const short8 b = *(const short8*)(WsU + (size_t)((c0 + c) * 16 + lm) * WROW + s * 32 + q * 8);
            acc[c] = __builtin_amdgcn_mfma_f32_16x16x32_bf16(a, b, acc[c], 0, 0, 0);
        }
    }
    __syncthreads();
    float* Cs = (float*)smem;                   // 16 KB, fits
#pragma unroll
    for (int c = 0; c < M / 32; ++c)
#pragma unroll
        for (int r = 0; r < 4; ++r)
            Cs[(size_t)(m0 + q * 4 + r) * M + (c0 + c) * 16 + lm] = acc[c][r];
    __syncthreads();

    for (int g = t; g < 64 * M / 4; g += THREADS_A) {
        const int r = g / (M / 4);
        const int gr = row0 + r;
        if (gr >= N) continue;
        const float4 o = *(const float4*)(Cs + (size_t)g * 4);
        const int col = (g % (M / 4)) * 4;
        ushort4 pk = {f2bf(o.x), f2bf(o.y), f2bf(o.z), f2bf(o.w)};
        *(ushort4*)(Yv + (size_t)gr * M + col) = pk;
    }
}

// ---- Kernel 2: per-bucket counting sort + row/dinv + H1 rescale ------------

__global__ __launch_bounds__(THREADS) void sortB_kernel(const unsigned* __restrict__ stagePad,
                                                        const int* __restrict__ cntg,
                                                        int nb, int N,
                                                        int* __restrict__ row,
                                                        float* __restrict__ dinv,
                                                        unsigned* __restrict__ srt,
                                                        unsigned* __restrict__ H1) {
    __shared__ unsigned buf[SORT_CAP];
    __shared__ int cnt[BKT], cur[BKT], scn[BKT];
    __shared__ float dv[BKT];
    __shared__ int red[THREADS];
    const int b = blockIdx.x, t = threadIdx.x;
    // Bucket prefix: bs = sum(cntg[0..b-1]) via strided loads + tree reduce.
    int part = 0;
    for (int j = t; j < b; j += THREADS) part += cntg[j];
    red[t] = part;
    __syncthreads();
#pragma unroll
    for (int off = THREADS / 2; off > 0; off >>= 1) {
        if (t < off) red[t] += red[t + off];
        __syncthreads();
    }
    const int bs = red[0];
    const int m = cntg[b];
    const unsigned* base = stagePad + (size_t)b * CAP;
    cnt[t] = 0;
    __syncthreads();
    for (int i = t; i < m; i += THREADS) {
        const unsigned v = base[i];
        buf[i] = v;
        atomicAdd(&cnt[v >> 17], 1);
    }
    __syncthreads();
    const int c = cnt[t];
    scn[t] = c;
    __syncthreads();
    for (int off = 1; off < BKT; off <<= 1) {
        int u = (t >= off) ? scn[t - off] : 0;
        __syncthreads();
        scn[t] += u;
        __syncthreads();
    }
    const int excl = scn[t] - c;
    cur[t] = excl;
    const float d = rsqrtf((float)c + 1.0f);
    dv[t] = d;
    const int node = b * BKT + t;
    if (node < N) {
        row[node] = bs + excl;
        dinv[node] = d;
    }
    __syncthreads();
    for (int i = t; i < m; i += THREADS) {
        const unsigned v = buf[i];
        const int pos = atomicAdd(&cur[v >> 17], 1);
        srt[bs + pos] = v & 0x1FFFFu;
    }
    // H1 rescale by dinv (R15 mechanism; bufH mostly L2-resident).
    const unsigned node0 = (unsigned)b * BKT;
    const int nn = min(BKT, N - (int)node0);
    unsigned* Hrow = H1 + node0 * 32u;
    for (int i = t; i < nn * 32; i += THREADS) {
        const float di = dv[i >> 5];
        const unsigned v = Hrow[i];
        const float lo = bflo(v) * di;
        const float hi = bfhi(v) * di;
        Hrow[i] = ((unsigned)f2bf(hi) << 16) | (unsigned)f2bf(lo);
    }
}

// ---- Fused aggregate + row-local MFMA matmul (R18 version, best measured) --
// Block owns 64 nodes; 8 waves, wave w handles nodes w*8..w*8+7 sequentially.
// Phase 1 (gather): 16 lanes/edge (dwordx2), 4 edges per wave-instr; chunk
// idx vectors prefetched one node ahead.  relu(dinv*(Hself+sum)+abias) ->
// bf16 LDS tile Rl[64][72u].
// Phase 2 (MFMA):  Y[64][M] = Rl @ W; wave = (row-strip w>>1, col-half w&1).
// MODE 1: Y *= dinv -> bf16 pair table.  MODE 2: Y += fbias -> fp32 out.

template <int M, int MODE>
__global__ __launch_bounds__(THREADS_A) void aggmm_kernel(const unsigned* __restrict__ srt,
                                                          const int* __restrict__ row,
                                                          const float* __restrict__ dinv,
                                                          const unsigned* __restrict__ H2,
                                                          const float* __restrict__ abias,
                                                          const float* __restrict__ W,
                                                          const float* __restrict__ fbias,
                                                          void* __restrict__ Yv,
                                                          int N, int E) {
    constexpr int K = 64;
    constexpr int RROW = 36;                 // relu-tile row stride in dwords (72 ushorts)
    constexpr int RB = 64 * RROW * 4;        // 9216 B
    constexpr int WROW = K + 8;              // 72 ushorts
    constexpr int WB = M * WROW * 2;
    constexpr int CB = 64 * M * 4;
    constexpr int SMEM = (RB + WB > CB) ? (RB + WB) : CB;
    __shared__ __align__(16) char smem[SMEM];
    const int t = threadIdx.x;
    const int w = t >> 6, lane = t & 63;
    const int row0 = blockIdx.x * 64;

    // Stage W^T bf16 (phase 1 doesn't read it; barrier below covers it).
    ushort_t* WsU = (ushort_t*)(smem + RB);
    for (int i = t; i < K * M; i += THREADS_A) {
        const int k = i / M, m = i % M;
        WsU[m * WROW + k] = f2bf(W[i]);
    }

    // Phase 1: gather+relu for this wave's 8 nodes.
    unsigned* Rl = (unsigned*)smem;
    const int col2 = lane & 15;              // dword-pair within 32-dword row
    const int slot = lane >> 4;              // edge slot 0..3
    const unsigned roff = (unsigned)(col2 * 2);
    const unsigned cap = (unsigned)(N - 1);
    const int node00 = row0 + w * 8;
    // Wave-invariant bias (hoisted off the per-node chain).
    const float4 bias4 = *(const float4*)(abias + col2 * 4);
    // Row/dinv prefetch: lanes 0..9 hold row[node00+lane] (E past the end).
    int rv;
    float dvv;
    {
        const int ridx = node00 + (int)lane;
        const bool okr = ridx < N;
        rv = okr ? row[ridx] : E;
        dvv = okr ? dinv[ridx] : 0.0f;
    }
    // Prefetch node-0 chunk-0 idx (16 lanes cooperative, broadcast pattern).
    int sc = __shfl(rv, 0, 64);
    int ec = __shfl(rv, 1, 64);
    unsigned idx0 = srt[sc + col2];
#pragma unroll 1
    for (int i = 0; i < 8; ++i) {
        const int node = node00 + i;
        if (node >= N) break;
        const int start = sc, end = ec;
        unsigned idx = idx0;
        if (i < 7) {  // prefetch next node's chunk-0 idx during this node
            sc = __shfl(rv, i + 1, 64);
            ec = __shfl(rv, i + 2, 64);
            idx0 = srt[sc + col2];
        }
        // Self-loop row, issued early (independent of gathers).
        const uint2 sv = *(const uint2*)(H2 + (((unsigned)node << 5) + roff));
        f32x2 a0 = {0.0f, 0.0f}, a1 = {0.0f, 0.0f};
        int base = start;
        while (base + 16 <= end) {
            unsigned idxn = 0;
            if (base + 16 < end)  // prefetch next chunk idx before the adds
                idxn = srt[base + 16 + col2];
#pragma unroll
            for (int g = 0; g < 4; ++g) {
                const unsigned r = (unsigned)__shfl((int)idx, g * 4 + slot, 64);
                const uint2 v = *(const uint2*)(H2 + ((r << 5) + roff));
                a0 += (f32x2){bflo(v.x), bfhi(v.x)};
                a1 += (f32x2){bflo(v.y), bfhi(v.y)};
            }
            base += 16;
            idx = idxn;
        }
        const int rem = end - base;
        if (rem > 0) {
#pragma unroll
            for (int g = 0; g < 4; ++g) {
                if (g * 4 >= rem) break;               // wave-uniform
                const int e = g * 4 + slot;
                unsigned r = (unsigned)__shfl((int)idx, e, 64) & 0x1FFFFu;
                r = min(r, cap);                       // garbage past end
                uint2 v = *(const uint2*)(H2 + ((r << 5) + roff));
                const bool ok = e < rem;
                v.x = ok ? v.x : 0u;
                v.y = ok ? v.y : 0u;
                a0 += (f32x2){bflo(v.x), bfhi(v.x)};
                a1 += (f32x2){bflo(v.y), bfhi(v.y)};
            }
        }
        // Reduce across the 4 edge slots (lanes 16 apart share col2).
        a0.x += __shfl_xor(a0.x, 16, 64);
        a0.y += __shfl_xor(a0.y, 16, 64);
        a1.x += __shfl_xor(a1.x, 16, 64);
        a1.y += __shfl_xor(a1.y, 16, 64);
        a0.x += __shfl_xor(a0.x, 32, 64);
        a0.y += __shfl_xor(a0.y, 32, 64);
        a1.x += __shfl_xor(a1.x, 32, 64);
        a1.y += __shfl_xor(a1.y, 32, 64);
        const float d = __shfl(dvv, i, 64);
        if (slot == 0) {
            const float o0 = fmaxf(fmaf(a0.x + bflo(sv.x), d, bias4.x), 0.0f);
            const float o1 = fmaxf(fmaf(a0.y + bfhi(sv.x), d, bias4.y), 0.0f);
            const float o2 = fmaxf(fmaf(a1.x + bflo(sv.y), d, bias4.z), 0.0f);
            const float o3 = fmaxf(fmaf(a1.y + bfhi(sv.y), d, bias4.w), 0.0f);
            uint2 pk;
            pk.x = ((unsigned)f2bf(o1) << 16) | (unsigned)f2bf(o0);
            pk.y = ((unsigned)f2bf(o3) << 16) | (unsigned)f2bf(o2);
            *(uint2*)(Rl + (size_t)(w * 8 + i) * RROW + col2 * 2) = pk;
        }
    }
    __syncthreads();

    // Phase 2: MFMA over the relu tile. Wave = (row-strip, col-half).
    constexpr int TW = M / 32;               // col tiles per wave (64->2, 32->1)
    const int m0 = (w >> 1) * 16, lm = lane & 15, q = lane >> 4;
    const int c0 = (w & 1) * TW;
    f32x4 acc[TW];
#pragma unroll
    for (int c = 0; c < TW; ++c) acc[c] = (f32x4)0.0f;
#pragma unroll
    for (int s = 0; s < K / 32; ++s) {
        const short8 a = *(const short8*)((const ushort_t*)Rl + (size_t)(m0 + lm) * 72 + s * 32 + q * 8);
#pragma unroll
        for (int c = 0; c < TW; ++c) {
            const short8 b = *(const short8*)(WsU + (size_t)((c0 + c) * 16 + lm) * WROW + s * 32 + q * 8);
            acc[c] = __builtin_amdgcn_mfma_f32_16x16x32_bf16(a, b, acc[c], 0, 0, 0);
        }
    }
    __syncthreads();   // Rl/Ws dead; reuse as C [64][M] f32
    float* Cs = (float*)smem;
#pragma unroll
    for (int c = 0; c < TW; ++c)
#pragma unroll
        for (int r = 0; r < 4; ++r)
            Cs[(size_t)(m0 + q * 4 + r) * M + (c0 + c) * 16 + lm] = acc[c][r];
    __syncthreads();

    for (int g = t; g < 64 * M / 4; g += THREADS_A) {
        const int r = g / (M / 4);
        const int gr = row0 + r;
        if (gr >= N) continue;
        float4 o = *(const float4*)(Cs + (size_t)g * 4);
        const int col = (g % (M / 4)) * 4;
        if (MODE == 1) {
            const float d = dinv[gr];
            o.x *= d; o.y *= d; o.z *= d; o.w *= d;
            ushort4 pk = {f2bf(o.x), f2bf(o.y), f2bf(o.z), f2bf(o.w)};
            *(ushort4*)((ushort_t*)Yv + (size_t)gr * M + col) = pk;
        } else {
            o.x += fbias[col]; o.y += fbias[col + 1];
            o.z += fbias[col + 2]; o.w += fbias[col + 3];
            *(float4*)((float*)Yv + (size_t)gr * M + col) = o;
        }
    }
}

// ---- Launch ----------------------------------------------------------------

extern "C" void kernel_launch(void* const* d_in, const int* in_sizes, int n_in,
                              void* d_out, int out_size, void* d_ws, size_t ws_size,
                              hipStream_t stream) {
    const float* x   = (const float*)d_in[0];
    const int*   ei  = (const int*)d_in[1];   // [2, E] int32
    const float* W1  = (const float*)d_in[3];
    const float* b1  = (const float*)d_in[4];
    const float* W2  = (const float*)d_in[5];
    const float* b2  = (const float*)d_in[6];
    const float* Wfc = (const float*)d_in[7];
    const float* bfc = (const float*)d_in[8];
    float* out = (float*)d_out;

    const int N = in_sizes[0] / 128;
    const int E = in_sizes[1] / 2;
    const int* src = ei;
    const int* dst = ei + E;

    const int nb   = (N + BKT - 1) / BKT;     // 391 buckets
    const int nblk = (E + EPB - 1) / EPB;     // 391 edge-chunks

    // Workspace (256 B-aligned slices).
    char* p = (char*)d_ws;
    auto alloc = [&](size_t bytes) { char* r = p; p += (bytes + 255) & ~(size_t)255; return r; };
    int*      cntg   = (int*)alloc((size_t)nb * 4);
    unsigned* srt    = (unsigned*)alloc((size_t)E * 4);
    int*      row    = (int*)alloc((size_t)N * 4);     // also absorbs agg tail over-reads
    float*    dinv   = (float*)alloc((size_t)N * 4);
    ushort_t* bufH   = (ushort_t*)alloc((size_t)N * 64 * 2);   // H1 table (bf16)
    ushort_t* bufR   = (ushort_t*)alloc((size_t)N * 64 * 2);   // H2 table; doubles as stagePad
    unsigned* stagePad = (unsigned*)bufR;     // nb*CAP*4 = 12.61 MB <= 12.8 MB, dead before aggmm-1

    const int mmB = (N + 63) / 64;

    // 0) zero bucket counters (kernel, not hipMemsetAsync: graph-capture-safe).
    zeroK_kernel<<<1, BIN_T, 0, stream>>>(cntg, nb);
    // 1) fused: binA partition (blocks<nblk) || mm1 MFMA unscaled (blocks>=nblk).
    binmm_kernel<128, 64><<<nblk + mmB, THREADS_A, 0, stream>>>(
        src, dst, E, nb, nblk, cntg, stagePad, x, W1, bufH, N);
    // 2) per-bucket counting sort -> srt, row, dinv; rescales H1 by dinv.
    sortB_kernel<<<nb, THREADS, 0, stream>>>(stagePad, cntg, nb, N, row, dinv, srt,
                                             (unsigned*)bufH);
    // 3) agg layer1 + mm2 fused -> H2 table (bf16, *dinv).
    aggmm_kernel<64, 1><<<mmB, THREADS_A, 0, stream>>>(
        srt, row, dinv, (const unsigned*)bufH, b1, W2, nullptr, bufR, N, E);
    // 4) agg layer2 + fc fused -> fp32 out (+bfc).
    aggmm_kernel<32, 2><<<mmB, THREADS_A, 0, stream>>>(
        srt, row, dinv, (const unsigned*)bufR, b2, Wfc, bfc, out, N, E);
}

// Round 12
// 223.888 us; speedup vs baseline: 1.2375x; 1.0119x over previous
//
#include <hip/hip_runtime.h>

// GCN: 2x (GCNConv + ReLU) + FC.  N=100000, E=1600000, F: 128 -> 64 -> 64 -> 32. fp32.
//
// R15: mm2/fc fused into agg kernels (row-local). aggmm block owns 64 nodes.
// R16-R18: aggmm gather restructures; 49 -> 42.7us (R18 best, kept verbatim).
// R19/R19b: binA range-reservation partition. -> 228.9
// R20/R21: EPB halving, aggmm unroll fast path: regressed; reverted.
// R22: banked best combo: 226.8us.
// R23: per-edge global deg atomics: +35us coherence stall. Reverted.
// R24: sort||mm1 + LDS degree histogram: 64-way LDS-atomic hotspot. Reverted.
// R25: binA||mm1 fusion (independent data): NEUTRAL 226.6 - the fused 51.2KB
//   LDS capped binA blocks at 3/CU, cancelling the saved gap.
// R26: make the fusion pay + de-barrier the partition:
//  - mm1 stages X as bf16 (convert on store): fused SMEM 51.2->34.8KB ->
//    4 blocks/CU; frag build = direct ds_read_b128 (no per-use f2bf).
//  - binA drops ebuf (re-reads src/dst from L2 in reorder): 47->30.8KB;
//    512-wide scan -> wave-shfl scan (18 barriers -> 2).
//  - sortB drops its 32KB buf (re-reads L2-resident stage in pass 2), both
//    scans -> shfl: LDS ~3KB -> 8 blocks/CU (was 4), barriers ~20 -> 4.
// Pipeline (5): zeroK -> binmm(binA||mm1) -> sortB(+H1 rescale) ->
//               aggmm(M=64,*dinv,bf16) -> aggmm(M=32,+bias,f32).

#define THREADS 256
#define THREADS_A 512
#define BIN_T 512
#define EPB 4096
#define BKT 256
#define CAP 8064
#define SORT_CAP 8192

typedef unsigned short ushort_t;
typedef __attribute__((ext_vector_type(8))) short short8;
typedef __attribute__((ext_vector_type(4))) float f32x4;
typedef __attribute__((ext_vector_type(2))) float f32x2;

__device__ __forceinline__ ushort_t f2bf(float f) {  // round-to-nearest-even
    unsigned u = __float_as_uint(f);
    u += 0x7FFFu + ((u >> 16) & 1u);
    return (ushort_t)(u >> 16);
}
__device__ __forceinline__ float bflo(unsigned v) { return __uint_as_float(v << 16); }
__device__ __forceinline__ float bfhi(unsigned v) { return __uint_as_float(v & 0xFFFF0000u); }

// ---- Kernel 0: zero the bucket counters (graph-capture-safe memset) --------

__global__ __launch_bounds__(BIN_T) void zeroK_kernel(int* __restrict__ p, int n) {
    const int i = (int)threadIdx.x;
    if (i < n) p[i] = 0;
}

// ---- Kernel 1: binmm - role-split binA (blocks<nblk) || mm1 (blocks>=nblk) -
// binA: bucket count + range reservation + coalesced scatter (30.8KB LDS,
//       wave-shfl scan).  mm1: 64-row MFMA tile, UNSCALED bf16 out, X staged
//       bf16 (34.8KB LDS).  Fused SMEM 34.8KB -> 4 blocks/CU.

template <int K, int M>
__global__ __launch_bounds__(THREADS_A) void binmm_kernel(const int* __restrict__ src,
                                                          const int* __restrict__ dst, int E,
                                                          int nb, int nblk,
                                                          int* __restrict__ cntg,
                                                          unsigned* __restrict__ stagePad,
                                                          const float* __restrict__ Xf,
                                                          const float* __restrict__ W,
                                                          ushort_t* __restrict__ Yv, int N) {
    constexpr int XROWU = K + 8;               // 136 ushorts
    constexpr int XB = 64 * XROWU * 2;         // 17408 B
    constexpr int WROW = K + 8;                // 136 ushorts
    constexpr int WB = M * WROW * 2;           // 17408 B -> mm1 = 34816 B
    constexpr int BA_ = EPB * 4 + EPB * 2 + BIN_T * 4 * 3 + 32;  // 30752 B
    constexpr int CB = 64 * M * 4;             // 16384 B (reuses smem[0..))
    constexpr int MM_ = XB + WB;
    constexpr int SMEM = (MM_ > BA_) ? ((MM_ > CB) ? MM_ : CB) : BA_;
    __shared__ __align__(16) char smem[SMEM];
    const int t = threadIdx.x;
    const int lane = t & 63, wid = t >> 6;

    if ((int)blockIdx.x < nblk) {
        // ---------------- binA path ----------------
        unsigned* ebuf2 = (unsigned*)smem;                 // 16384 B
        ushort_t* ebkt2 = (ushort_t*)(smem + EPB * 4);     //  8192 B
        int* cnt  = (int*)(smem + EPB * 4 + EPB * 2);      //  2048 B
        int* cur  = cnt + BIN_T;                           //  2048 B
        int* gb   = cur + BIN_T;                           //  2048 B
        int* wsum = gb + BIN_T;                            //    32 B
        const int e0 = blockIdx.x * EPB;
        const int n = min(EPB, E - e0);
        cnt[t] = 0;
        __syncthreads();
        for (int i = t; i < n; i += BIN_T)
            atomicAdd(&cnt[dst[e0 + i] >> 8], 1);
        __syncthreads();
        // Wave-shfl inclusive scan of cnt over 512 threads (2 barriers).
        const int v = cnt[t];
        int sv = v;
#pragma unroll
        for (int off = 1; off < 64; off <<= 1) {
            const int u = __shfl_up(sv, off, 64);
            if (lane >= off) sv += u;
        }
        if (lane == 63) wsum[wid] = sv;
        __syncthreads();
        int wbase = 0;
#pragma unroll
        for (int j = 0; j < 8; ++j) wbase += (j < wid) ? wsum[j] : 0;
        const int excl = sv + wbase - v;
        if (t < nb && v > 0) {
            const int resv = atomicAdd(&cntg[t], v);
            gb[t] = t * CAP + resv - excl;
        }
        cur[t] = excl;
        __syncthreads();
        // Reorder into bucket-sorted LDS (src/dst re-read, L2-hot).
        for (int i = t; i < n; i += BIN_T) {
            const int d = dst[e0 + i];
            const unsigned s = (unsigned)src[e0 + i];
            const int b = d >> 8;
            const int p = atomicAdd(&cur[b], 1);
            ebuf2[p] = ((unsigned)(d & (BKT - 1)) << 17) | s;
            ebkt2[p] = (ushort_t)b;
        }
        __syncthreads();
        // Coalesced-run output (address increments by 1 within a bucket run).
        for (int i = t; i < n; i += BIN_T)
            stagePad[gb[(int)ebkt2[i]] + i] = ebuf2[i];
        return;
    }

    // ---------------- mm1 path (unscaled; 8 waves; bf16-staged X) -----------
    const int row0 = ((int)blockIdx.x - nblk) * 64;
    ushort_t* XsU = (ushort_t*)smem;
    ushort_t* WsU = (ushort_t*)(smem + XB);
    for (int i = t; i < K * M; i += THREADS_A) {
        const int k = i / M, m = i % M;
        WsU[m * WROW + k] = f2bf(W[i]);
    }
    for (int i = t; i < 64 * K / 4; i += THREADS_A) {
        const int r = i / (K / 4), kc = i % (K / 4);
        const unsigned gr = (unsigned)min(row0 + r, N - 1);
        const float4 f = *(const float4*)(Xf + (size_t)gr * K + kc * 4);
        ushort4 pk = {f2bf(f.x), f2bf(f.y), f2bf(f.z), f2bf(f.w)};
        *(ushort4*)(XsU + (size_t)r * XROWU + kc * 4) = pk;
    }
    __syncthreads();

    const int w = wid;
    const int m0 = (w >> 1) * 16, lm = lane & 15, q = lane >> 4;
    const int c0 = (w & 1) * (M / 32);          // 2 col-tiles per wave (M=64)
    f32x4 acc[M / 32];
#pragma unroll
    for (int c = 0; c < M / 32; ++c) acc[c] = (f32x4)0.0f;

#pragma unroll
    for (int s = 0; s < K / 32; ++s) {
        const short8 a = *(const short8*)(XsU + (size_t)(m0 + lm) * XROWU + s * 32 + q * 8);
#pragma unroll
        for (int c = 0; c < M / 32; ++c) {
            const short8 b = *(const short8*)(WsU + (size_t)((c0 + c) * 16 + lm) * WROW + s * 32 + q * 8);
            acc[c] = __builtin_amdgcn_mfma_f32_16x16x32_bf16(a, b, acc[c], 0, 0, 0);
        }
    }
    __syncthreads();
    float* Cs = (float*)smem;                   // 16 KB, fits
#pragma unroll
    for (int c = 0; c < M / 32; ++c)
#pragma unroll
        for (int r = 0; r < 4; ++r)
            Cs[(size_t)(m0 + q * 4 + r) * M + (c0 + c) * 16 + lm] = acc[c][r];
    __syncthreads();

    for (int g = t; g < 64 * M / 4; g += THREADS_A) {
        const int r = g / (M / 4);
        const int gr = row0 + r;
        if (gr >= N) continue;
        const float4 o = *(const float4*)(Cs + (size_t)g * 4);
        const int col = (g % (M / 4)) * 4;
        ushort4 pk = {f2bf(o.x), f2bf(o.y), f2bf(o.z), f2bf(o.w)};
        *(ushort4*)(Yv + (size_t)gr * M + col) = pk;
    }
}

// ---- Kernel 2: per-bucket counting sort + row/dinv + H1 rescale ------------
// No LDS edge buffer (stage re-read from L2); shfl scans; ~3KB LDS ->
// 8 blocks/CU.

__global__ __launch_bounds__(THREADS) void sortB_kernel(const unsigned* __restrict__ stagePad,
                                                        const int* __restrict__ cntg,
                                                        int nb, int N,
                                                        int* __restrict__ row,
                                                        float* __restrict__ dinv,
                                                        unsigned* __restrict__ srt,
                                                        unsigned* __restrict__ H1) {
    __shared__ int cnt[BKT], cur[BKT];
    __shared__ float dv[BKT];
    __shared__ int wsum[4];
    const int b = blockIdx.x, t = threadIdx.x;
    const int lane = t & 63, wid = t >> 6;
    // Bucket prefix: bs = sum(cntg[0..b-1]) via strided loads + shfl reduce.
    int part = 0;
    for (int j = t; j < b; j += THREADS) part += cntg[j];
#pragma unroll
    for (int off = 32; off > 0; off >>= 1) part += __shfl_xor(part, off, 64);
    if (lane == 0) wsum[wid] = part;
    cnt[t] = 0;
    __syncthreads();
    const int bs = wsum[0] + wsum[1] + wsum[2] + wsum[3];
    const int m = cntg[b];
    const unsigned* base = stagePad + (size_t)b * CAP;
    for (int i = t; i < m; i += THREADS)
        atomicAdd(&cnt[base[i] >> 17], 1);
    __syncthreads();
    // Wave-shfl inclusive scan over the 256 counts.
    const int c = cnt[t];
    int sv = c;
#pragma unroll
    for (int off = 1; off < 64; off <<= 1) {
        const int u = __shfl_up(sv, off, 64);
        if (lane >= off) sv += u;
    }
    if (lane == 63) wsum[wid] = sv;
    __syncthreads();
    int wbase = 0;
#pragma unroll
    for (int j = 0; j < 4; ++j) wbase += (j < wid) ? wsum[j] : 0;
    const int excl = sv + wbase - c;
    cur[t] = excl;
    const float d = rsqrtf((float)c + 1.0f);
    dv[t] = d;
    const int node = b * BKT + t;
    if (node < N) {
        row[node] = bs + excl;
        dinv[node] = d;
    }
    __syncthreads();
    for (int i = t; i < m; i += THREADS) {
        const unsigned v = base[i];
        const int pos = atomicAdd(&cur[v >> 17], 1);
        srt[bs + pos] = v & 0x1FFFFu;
    }
    // H1 rescale by dinv (bufH mostly L2-resident).
    const unsigned node0 = (unsigned)b * BKT;
    const int nn = min(BKT, N - (int)node0);
    unsigned* Hrow = H1 + node0 * 32u;
    for (int i = t; i < nn * 32; i += THREADS) {
        const float di = dv[i >> 5];
        const unsigned v = Hrow[i];
        const float lo = bflo(v) * di;
        const float hi = bfhi(v) * di;
        Hrow[i] = ((unsigned)f2bf(hi) << 16) | (unsigned)f2bf(lo);
    }
}

// ---- Fused aggregate + row-local MFMA matmul (R18 version, best measured) --
// Block owns 64 nodes; 8 waves, wave w handles nodes w*8..w*8+7 sequentially.
// Phase 1 (gather): 16 lanes/edge (dwordx2), 4 edges per wave-instr; chunk
// idx vectors prefetched one node ahead.  relu(dinv*(Hself+sum)+abias) ->
// bf16 LDS tile Rl[64][72u].
// Phase 2 (MFMA):  Y[64][M] = Rl @ W; wave = (row-strip w>>1, col-half w&1).
// MODE 1: Y *= dinv -> bf16 pair table.  MODE 2: Y += fbias -> fp32 out.

template <int M, int MODE>
__global__ __launch_bounds__(THREADS_A) void aggmm_kernel(const unsigned* __restrict__ srt,
                                                          const int* __restrict__ row,
                                                          const float* __restrict__ dinv,
                                                          const unsigned* __restrict__ H2,
                                                          const float* __restrict__ abias,
                                                          const float* __restrict__ W,
                                                          const float* __restrict__ fbias,
                                                          void* __restrict__ Yv,
                                                          int N, int E) {
    constexpr int K = 64;
    constexpr int RROW = 36;                 // relu-tile row stride in dwords (72 ushorts)
    constexpr int RB = 64 * RROW * 4;        // 9216 B
    constexpr int WROW = K + 8;              // 72 ushorts
    constexpr int WB = M * WROW * 2;
    constexpr int CB = 64 * M * 4;
    constexpr int SMEM = (RB + WB > CB) ? (RB + WB) : CB;
    __shared__ __align__(16) char smem[SMEM];
    const int t = threadIdx.x;
    const int w = t >> 6, lane = t & 63;
    const int row0 = blockIdx.x * 64;

    // Stage W^T bf16 (phase 1 doesn't read it; barrier below covers it).
    ushort_t* WsU = (ushort_t*)(smem + RB);
    for (int i = t; i < K * M; i += THREADS_A) {
        const int k = i / M, m = i % M;
        WsU[m * WROW + k] = f2bf(W[i]);
    }

    // Phase 1: gather+relu for this wave's 8 nodes.
    unsigned* Rl = (unsigned*)smem;
    const int col2 = lane & 15;              // dword-pair within 32-dword row
    const int slot = lane >> 4;              // edge slot 0..3
    const unsigned roff = (unsigned)(col2 * 2);
    const unsigned cap = (unsigned)(N - 1);
    const int node00 = row0 + w * 8;
    // Wave-invariant bias (hoisted off the per-node chain).
    const float4 bias4 = *(const float4*)(abias + col2 * 4);
    // Row/dinv prefetch: lanes 0..9 hold row[node00+lane] (E past the end).
    int rv;
    float dvv;
    {
        const int ridx = node00 + (int)lane;
        const bool okr = ridx < N;
        rv = okr ? row[ridx] : E;
        dvv = okr ? dinv[ridx] : 0.0f;
    }
    // Prefetch node-0 chunk-0 idx (16 lanes cooperative, broadcast pattern).
    int sc = __shfl(rv, 0, 64);
    int ec = __shfl(rv, 1, 64);
    unsigned idx0 = srt[sc + col2];
#pragma unroll 1
    for (int i = 0; i < 8; ++i) {
        const int node = node00 + i;
        if (node >= N) break;
        const int start = sc, end = ec;
        unsigned idx = idx0;
        if (i < 7) {  // prefetch next node's chunk-0 idx during this node
            sc = __shfl(rv, i + 1, 64);
            ec = __shfl(rv, i + 2, 64);
            idx0 = srt[sc + col2];
        }
        // Self-loop row, issued early (independent of gathers).
        const uint2 sv = *(const uint2*)(H2 + (((unsigned)node << 5) + roff));
        f32x2 a0 = {0.0f, 0.0f}, a1 = {0.0f, 0.0f};
        int base = start;
        while (base + 16 <= end) {
            unsigned idxn = 0;
            if (base + 16 < end)  // prefetch next chunk idx before the adds
                idxn = srt[base + 16 + col2];
#pragma unroll
            for (int g = 0; g < 4; ++g) {
                const unsigned r = (unsigned)__shfl((int)idx, g * 4 + slot, 64);
                const uint2 v = *(const uint2*)(H2 + ((r << 5) + roff));
                a0 += (f32x2){bflo(v.x), bfhi(v.x)};
                a1 += (f32x2){bflo(v.y), bfhi(v.y)};
            }
            base += 16;
            idx = idxn;
        }
        const int rem = end - base;
        if (rem > 0) {
#pragma unroll
            for (int g = 0; g < 4; ++g) {
                if (g * 4 >= rem) break;               // wave-uniform
                const int e = g * 4 + slot;
                unsigned r = (unsigned)__shfl((int)idx, e, 64) & 0x1FFFFu;
                r = min(r, cap);                       // garbage past end
                uint2 v = *(const uint2*)(H2 + ((r << 5) + roff));
                const bool ok = e < rem;
                v.x = ok ? v.x : 0u;
                v.y = ok ? v.y : 0u;
                a0 += (f32x2){bflo(v.x), bfhi(v.x)};
                a1 += (f32x2){bflo(v.y), bfhi(v.y)};
            }
        }
        // Reduce across the 4 edge slots (lanes 16 apart share col2).
        a0.x += __shfl_xor(a0.x, 16, 64);
        a0.y += __shfl_xor(a0.y, 16, 64);
        a1.x += __shfl_xor(a1.x, 16, 64);
        a1.y += __shfl_xor(a1.y, 16, 64);
        a0.x += __shfl_xor(a0.x, 32, 64);
        a0.y += __shfl_xor(a0.y, 32, 64);
        a1.x += __shfl_xor(a1.x, 32, 64);
        a1.y += __shfl_xor(a1.y, 32, 64);
        const float d = __shfl(dvv, i, 64);
        if (slot == 0) {
            const float o0 = fmaxf(fmaf(a0.x + bflo(sv.x), d, bias4.x), 0.0f);
            const float o1 = fmaxf(fmaf(a0.y + bfhi(sv.x), d, bias4.y), 0.0f);
            const float o2 = fmaxf(fmaf(a1.x + bflo(sv.y), d, bias4.z), 0.0f);
            const float o3 = fmaxf(fmaf(a1.y + bfhi(sv.y), d, bias4.w), 0.0f);
            uint2 pk;
            pk.x = ((unsigned)f2bf(o1) << 16) | (unsigned)f2bf(o0);
            pk.y = ((unsigned)f2bf(o3) << 16) | (unsigned)f2bf(o2);
            *(uint2*)(Rl + (size_t)(w * 8 + i) * RROW + col2 * 2) = pk;
        }
    }
    __syncthreads();

    // Phase 2: MFMA over the relu tile. Wave = (row-strip, col-half).
    constexpr int TW = M / 32;               // col tiles per wave (64->2, 32->1)
    const int m0 = (w >> 1) * 16, lm = lane & 15, q = lane >> 4;
    const int c0 = (w & 1) * TW;
    f32x4 acc[TW];
#pragma unroll
    for (int c = 0; c < TW; ++c) acc[c] = (f32x4)0.0f;
#pragma unroll
    for (int s = 0; s < K / 32; ++s) {
        const short8 a = *(const short8*)((const ushort_t*)Rl + (size_t)(m0 + lm) * 72 + s * 32 + q * 8);
#pragma unroll
        for (int c = 0; c < TW; ++c) {
            const short8 b = *(const short8*)(WsU + (size_t)((c0 + c) * 16 + lm) * WROW + s * 32 + q * 8);
            acc[c] = __builtin_amdgcn_mfma_f32_16x16x32_bf16(a, b, acc[c], 0, 0, 0);
        }
    }
    __syncthreads();   // Rl/Ws dead; reuse as C [64][M] f32
    float* Cs = (float*)smem;
#pragma unroll
    for (int c = 0; c < TW; ++c)
#pragma unroll
        for (int r = 0; r < 4; ++r)
            Cs[(size_t)(m0 + q * 4 + r) * M + (c0 + c) * 16 + lm] = acc[c][r];
    __syncthreads();

    for (int g = t; g < 64 * M / 4; g += THREADS_A) {
        const int r = g / (M / 4);
        const int gr = row0 + r;
        if (gr >= N) continue;
        float4 o = *(const float4*)(Cs + (size_t)g * 4);
        const int col = (g % (M / 4)) * 4;
        if (MODE == 1) {
            const float d = dinv[gr];
            o.x *= d; o.y *= d; o.z *= d; o.w *= d;
            ushort4 pk = {f2bf(o.x), f2bf(o.y), f2bf(o.z), f2bf(o.w)};
            *(ushort4*)((ushort_t*)Yv + (size_t)gr * M + col) = pk;
        } else {
            o.x += fbias[col]; o.y += fbias[col + 1];
            o.z += fbias[col + 2]; o.w += fbias[col + 3];
            *(float4*)((float*)Yv + (size_t)gr * M + col) = o;
        }
    }
}

// ---- Launch ----------------------------------------------------------------

extern "C" void kernel_launch(void* const* d_in, const int* in_sizes, int n_in,
                              void* d_out, int out_size, void* d_ws, size_t ws_size,
                              hipStream_t stream) {
    const float* x   = (const float*)d_in[0];
    const int*   ei  = (const int*)d_in[1];   // [2, E] int32
    const float* W1  = (const float*)d_in[3];
    const float* b1  = (const float*)d_in[4];
    const float* W2  = (const float*)d_in[5];
    const float* b2  = (const float*)d_in[6];
    const float* Wfc = (const float*)d_in[7];
    const float* bfc = (const float*)d_in[8];
    float* out = (float*)d_out;

    const int N = in_sizes[0] / 128;
    const int E = in_sizes[1] / 2;
    const int* src = ei;
    const int* dst = ei + E;

    const int nb   = (N + BKT - 1) / BKT;     // 391 buckets
    const int nblk = (E + EPB - 1) / EPB;     // 391 edge-chunks

    // Workspace (256 B-aligned slices).
    char* p = (char*)d_ws;
    auto alloc = [&](size_t bytes) { char* r = p; p += (bytes + 255) & ~(size_t)255; return r; };
    int*      cntg   = (int*)alloc((size_t)nb * 4);
    unsigned* srt    = (unsigned*)alloc((size_t)E * 4);
    int*      row    = (int*)alloc((size_t)N * 4);     // also absorbs agg tail over-reads
    float*    dinv   = (float*)alloc((size_t)N * 4);
    ushort_t* bufH   = (ushort_t*)alloc((size_t)N * 64 * 2);   // H1 table (bf16)
    ushort_t* bufR   = (ushort_t*)alloc((size_t)N * 64 * 2);   // H2 table; doubles as stagePad
    unsigned* stagePad = (unsigned*)bufR;     // nb*CAP*4 = 12.61 MB <= 12.8 MB, dead before aggmm-1

    const int mmB = (N + 63) / 64;

    // 0) zero bucket counters (kernel, not hipMemsetAsync: graph-capture-safe).
    zeroK_kernel<<<1, BIN_T, 0, stream>>>(cntg, nb);
    // 1) fused: binA partition (blocks<nblk) || mm1 MFMA unscaled (blocks>=nblk).
    binmm_kernel<128, 64><<<nblk + mmB, THREADS_A, 0, stream>>>(
        src, dst, E, nb, nblk, cntg, stagePad, x, W1, bufH, N);
    // 2) per-bucket counting sort -> srt, row, dinv; rescales H1 by dinv.
    sortB_kernel<<<nb, THREADS, 0, stream>>>(stagePad, cntg, nb, N, row, dinv, srt,
                                             (unsigned*)bufH);
    // 3) agg layer1 + mm2 fused -> H2 table (bf16, *dinv).
    aggmm_kernel<64, 1><<<mmB, THREADS_A, 0, stream>>>(
        srt, row, dinv, (const unsigned*)bufH, b1, W2, nullptr, bufR, N, E);
    // 4) agg layer2 + fc fused -> fp32 out (+bfc).
    aggmm_kernel<32, 2><<<mmB, THREADS_A, 0, stream>>>(
        srt, row, dinv, (const unsigned*)bufR, b2, Wfc, bfc, out, N, E);
}

// Round 13
// 221.242 us; speedup vs baseline: 1.2523x; 1.0120x over previous
//
#include <hip/hip_runtime.h>

// GCN: 2x (GCNConv + ReLU) + FC.  N=100000, E=1600000, F: 128 -> 64 -> 64 -> 32. fp32.
//
// R15: mm2/fc fused into agg kernels (row-local). aggmm block owns 64 nodes.
// R16-R18: aggmm gather restructures; 49 -> 42.7us (R18 best, kept verbatim).
// R19/R19b: binA range-reservation partition. -> 228.9
// R22: banked best combo: 226.8us.
// R23: per-edge global deg atomics: +35us coherence stall. Reverted.
// R24: sort||mm1 + LDS degree histogram: LDS-atomic hotspot. Reverted.
// R25: binA||mm1 fusion: neutral (51.2KB LDS capped binA at 3 blocks/CU).
// R26: bf16-staged mm1 (fused 34.8KB -> 4 blocks/CU), slim binA (shfl scan),
//   slim sortB.  223.9us (best).  Gain < predicted: sortB has only 391
//   blocks = 1.5 blocks/CU - GRID is its occupancy cap, not LDS.
// R27: half-bucket sortB: 782 blocks (2 per bucket, ~3 blocks/CU).  Both
//   halves build the identical full-bucket histogram+scan (deterministic),
//   then each scatters only its 128-node half (disjoint srt ranges from the
//   shared exclusive scan - no cross-block coordination) and rescales only
//   its half's H1 rows (uint2-vectorized).  Count pass duplicated (+6.4MB
//   L2 reads) but per-block scatter/rescale halves and grid doubles.
//   binmm/aggmm/zeroK byte-identical to R26.
// Pipeline (5): zeroK -> binmm(binA||mm1) -> sortB(halves,+H1 rescale) ->
//               aggmm(M=64,*dinv,bf16) -> aggmm(M=32,+bias,f32).

#define THREADS 256
#define THREADS_A 512
#define BIN_T 512
#define EPB 4096
#define BKT 256
#define CAP 8064
#define SORT_CAP 8192

typedef unsigned short ushort_t;
typedef __attribute__((ext_vector_type(8))) short short8;
typedef __attribute__((ext_vector_type(4))) float f32x4;
typedef __attribute__((ext_vector_type(2))) float f32x2;

__device__ __forceinline__ ushort_t f2bf(float f) {  // round-to-nearest-even
    unsigned u = __float_as_uint(f);
    u += 0x7FFFu + ((u >> 16) & 1u);
    return (ushort_t)(u >> 16);
}
__device__ __forceinline__ float bflo(unsigned v) { return __uint_as_float(v << 16); }
__device__ __forceinline__ float bfhi(unsigned v) { return __uint_as_float(v & 0xFFFF0000u); }

// ---- Kernel 0: zero the bucket counters (graph-capture-safe memset) --------

__global__ __launch_bounds__(BIN_T) void zeroK_kernel(int* __restrict__ p, int n) {
    const int i = (int)threadIdx.x;
    if (i < n) p[i] = 0;
}

// ---- Kernel 1: binmm - role-split binA (blocks<nblk) || mm1 (blocks>=nblk) -
// binA: bucket count + range reservation + coalesced scatter (30.8KB LDS,
//       wave-shfl scan).  mm1: 64-row MFMA tile, UNSCALED bf16 out, X staged
//       bf16 (34.8KB LDS).  Fused SMEM 34.8KB -> 4 blocks/CU.

template <int K, int M>
__global__ __launch_bounds__(THREADS_A) void binmm_kernel(const int* __restrict__ src,
                                                          const int* __restrict__ dst, int E,
                                                          int nb, int nblk,
                                                          int* __restrict__ cntg,
                                                          unsigned* __restrict__ stagePad,
                                                          const float* __restrict__ Xf,
                                                          const float* __restrict__ W,
                                                          ushort_t* __restrict__ Yv, int N) {
    constexpr int XROWU = K + 8;               // 136 ushorts
    constexpr int XB = 64 * XROWU * 2;         // 17408 B
    constexpr int WROW = K + 8;                // 136 ushorts
    constexpr int WB = M * WROW * 2;           // 17408 B -> mm1 = 34816 B
    constexpr int BA_ = EPB * 4 + EPB * 2 + BIN_T * 4 * 3 + 32;  // 30752 B
    constexpr int CB = 64 * M * 4;             // 16384 B (reuses smem[0..))
    constexpr int MM_ = XB + WB;
    constexpr int SMEM = (MM_ > BA_) ? ((MM_ > CB) ? MM_ : CB) : BA_;
    __shared__ __align__(16) char smem[SMEM];
    const int t = threadIdx.x;
    const int lane = t & 63, wid = t >> 6;

    if ((int)blockIdx.x < nblk) {
        // ---------------- binA path ----------------
        unsigned* ebuf2 = (unsigned*)smem;                 // 16384 B
        ushort_t* ebkt2 = (ushort_t*)(smem + EPB * 4);     //  8192 B
        int* cnt  = (int*)(smem + EPB * 4 + EPB * 2);      //  2048 B
        int* cur  = cnt + BIN_T;                           //  2048 B
        int* gb   = cur + BIN_T;                           //  2048 B
        int* wsum = gb + BIN_T;                            //    32 B
        const int e0 = blockIdx.x * EPB;
        const int n = min(EPB, E - e0);
        cnt[t] = 0;
        __syncthreads();
        for (int i = t; i < n; i += BIN_T)
            atomicAdd(&cnt[dst[e0 + i] >> 8], 1);
        __syncthreads();
        // Wave-shfl inclusive scan of cnt over 512 threads (2 barriers).
        const int v = cnt[t];
        int sv = v;
#pragma unroll
        for (int off = 1; off < 64; off <<= 1) {
            const int u = __shfl_up(sv, off, 64);
            if (lane >= off) sv += u;
        }
        if (lane == 63) wsum[wid] = sv;
        __syncthreads();
        int wbase = 0;
#pragma unroll
        for (int j = 0; j < 8; ++j) wbase += (j < wid) ? wsum[j] : 0;
        const int excl = sv + wbase - v;
        if (t < nb && v > 0) {
            const int resv = atomicAdd(&cntg[t], v);
            gb[t] = t * CAP + resv - excl;
        }
        cur[t] = excl;
        __syncthreads();
        // Reorder into bucket-sorted LDS (src/dst re-read, L2-hot).
        for (int i = t; i < n; i += BIN_T) {
            const int d = dst[e0 + i];
            const unsigned s = (unsigned)src[e0 + i];
            const int b = d >> 8;
            const int p = atomicAdd(&cur[b], 1);
            ebuf2[p] = ((unsigned)(d & (BKT - 1)) << 17) | s;
            ebkt2[p] = (ushort_t)b;
        }
        __syncthreads();
        // Coalesced-run output (address increments by 1 within a bucket run).
        for (int i = t; i < n; i += BIN_T)
            stagePad[gb[(int)ebkt2[i]] + i] = ebuf2[i];
        return;
    }

    // ---------------- mm1 path (unscaled; 8 waves; bf16-staged X) -----------
    const int row0 = ((int)blockIdx.x - nblk) * 64;
    ushort_t* XsU = (ushort_t*)smem;
    ushort_t* WsU = (ushort_t*)(smem + XB);
    for (int i = t; i < K * M; i += THREADS_A) {
        const int k = i / M, m = i % M;
        WsU[m * WROW + k] = f2bf(W[i]);
    }
    for (int i = t; i < 64 * K / 4; i += THREADS_A) {
        const int r = i / (K / 4), kc = i % (K / 4);
        const unsigned gr = (unsigned)min(row0 + r, N - 1);
        const float4 f = *(const float4*)(Xf + (size_t)gr * K + kc * 4);
        ushort4 pk = {f2bf(f.x), f2bf(f.y), f2bf(f.z), f2bf(f.w)};
        *(ushort4*)(XsU + (size_t)r * XROWU + kc * 4) = pk;
    }
    __syncthreads();

    const int w = wid;
    const int m0 = (w >> 1) * 16, lm = lane & 15, q = lane >> 4;
    const int c0 = (w & 1) * (M / 32);          // 2 col-tiles per wave (M=64)
    f32x4 acc[M / 32];
#pragma unroll
    for (int c = 0; c < M / 32; ++c) acc[c] = (f32x4)0.0f;

#pragma unroll
    for (int s = 0; s < K / 32; ++s) {
        const short8 a = *(const short8*)(XsU + (size_t)(m0 + lm) * XROWU + s * 32 + q * 8);
#pragma unroll
        for (int c = 0; c < M / 32; ++c) {
            const short8 b = *(const short8*)(WsU + (size_t)((c0 + c) * 16 + lm) * WROW + s * 32 + q * 8);
            acc[c] = __builtin_amdgcn_mfma_f32_16x16x32_bf16(a, b, acc[c], 0, 0, 0);
        }
    }
    __syncthreads();
    float* Cs = (float*)smem;                   // 16 KB, fits
#pragma unroll
    for (int c = 0; c < M / 32; ++c)
#pragma unroll
        for (int r = 0; r < 4; ++r)
            Cs[(size_t)(m0 + q * 4 + r) * M + (c0 + c) * 16 + lm] = acc[c][r];
    __syncthreads();

    for (int g = t; g < 64 * M / 4; g += THREADS_A) {
        const int r = g / (M / 4);
        const int gr = row0 + r;
        if (gr >= N) continue;
        const float4 o = *(const float4*)(Cs + (size_t)g * 4);
        const int col = (g % (M / 4)) * 4;
        ushort4 pk = {f2bf(o.x), f2bf(o.y), f2bf(o.z), f2bf(o.w)};
        *(ushort4*)(Yv + (size_t)gr * M + col) = pk;
    }
}

// ---- Kernel 2: half-bucket counting sort + row/dinv + H1 rescale -----------
// 2 blocks per bucket (782 total): both build the full-bucket histogram+scan
// (deterministic), each scatters + rescales only its 128-node half.

__global__ __launch_bounds__(THREADS) void sortB_kernel(const unsigned* __restrict__ stagePad,
                                                        const int* __restrict__ cntg,
                                                        int nb, int N,
                                                        int* __restrict__ row,
                                                        float* __restrict__ dinv,
                                                        unsigned* __restrict__ srt,
                                                        unsigned* __restrict__ H1) {
    __shared__ int cnt[BKT], cur[BKT];
    __shared__ float dv[BKT];
    __shared__ int wsum[4];
    const int blk = blockIdx.x;
    const int b = blk >> 1;                    // bucket
    const int h = blk & 1;                     // half (0: nodes 0-127, 1: 128-255)
    const int t = threadIdx.x;
    const int lane = t & 63, wid = t >> 6;
    // Bucket prefix: bs = sum(cntg[0..b-1]) via strided loads + shfl reduce.
    int part = 0;
    for (int j = t; j < b; j += THREADS) part += cntg[j];
#pragma unroll
    for (int off = 32; off > 0; off >>= 1) part += __shfl_xor(part, off, 64);
    if (lane == 0) wsum[wid] = part;
    cnt[t] = 0;
    __syncthreads();
    const int bs = wsum[0] + wsum[1] + wsum[2] + wsum[3];
    const int m = cntg[b];
    const unsigned* base = stagePad + (size_t)b * CAP;
    for (int i = t; i < m; i += THREADS)
        atomicAdd(&cnt[base[i] >> 17], 1);
    __syncthreads();
    // Wave-shfl inclusive scan over the 256 counts (identical in both halves).
    const int c = cnt[t];
    int sv = c;
#pragma unroll
    for (int off = 1; off < 64; off <<= 1) {
        const int u = __shfl_up(sv, off, 64);
        if (lane >= off) sv += u;
    }
    if (lane == 63) wsum[wid] = sv;
    __syncthreads();
    int wbase = 0;
#pragma unroll
    for (int j = 0; j < 4; ++j) wbase += (j < wid) ? wsum[j] : 0;
    const int excl = sv + wbase - c;
    cur[t] = excl;
    const float d = rsqrtf((float)c + 1.0f);
    dv[t] = d;
    const int node = b * BKT + t;
    if ((t >> 7) == h && node < N) {           // my half writes row/dinv
        row[node] = bs + excl;
        dinv[node] = d;
    }
    __syncthreads();
    // Scatter only my half's entries (disjoint srt ranges via shared scan).
    for (int i = t; i < m; i += THREADS) {
        const unsigned v = base[i];
        const int l = (int)(v >> 17);
        if ((l >> 7) == h) {
            const int pos = atomicAdd(&cur[l], 1);
            srt[bs + pos] = v & 0x1FFFFu;
        }
    }
    // H1 rescale for my half's 128 nodes (uint2-vectorized; L2-resident).
    const int node0 = b * BKT + (h << 7);
    const int nn = min(128, N - node0);
    if (nn > 0) {
        unsigned* Hrow = H1 + (unsigned)node0 * 32u;
        for (int i = t; i < nn * 16; i += THREADS) {
            const float di = dv[(h << 7) + (i >> 4)];
            uint2 v = *(uint2*)(Hrow + (size_t)i * 2);
            const float lo0 = bflo(v.x) * di, hi0 = bfhi(v.x) * di;
            const float lo1 = bflo(v.y) * di, hi1 = bfhi(v.y) * di;
            v.x = ((unsigned)f2bf(hi0) << 16) | (unsigned)f2bf(lo0);
            v.y = ((unsigned)f2bf(hi1) << 16) | (unsigned)f2bf(lo1);
            *(uint2*)(Hrow + (size_t)i * 2) = v;
        }
    }
}

// ---- Fused aggregate + row-local MFMA matmul (R18 version, best measured) --
// Block owns 64 nodes; 8 waves, wave w handles nodes w*8..w*8+7 sequentially.
// Phase 1 (gather): 16 lanes/edge (dwordx2), 4 edges per wave-instr; chunk
// idx vectors prefetched one node ahead.  relu(dinv*(Hself+sum)+abias) ->
// bf16 LDS tile Rl[64][72u].
// Phase 2 (MFMA):  Y[64][M] = Rl @ W; wave = (row-strip w>>1, col-half w&1).
// MODE 1: Y *= dinv -> bf16 pair table.  MODE 2: Y += fbias -> fp32 out.

template <int M, int MODE>
__global__ __launch_bounds__(THREADS_A) void aggmm_kernel(const unsigned* __restrict__ srt,
                                                          const int* __restrict__ row,
                                                          const float* __restrict__ dinv,
                                                          const unsigned* __restrict__ H2,
                                                          const float* __restrict__ abias,
                                                          const float* __restrict__ W,
                                                          const float* __restrict__ fbias,
                                                          void* __restrict__ Yv,
                                                          int N, int E) {
    constexpr int K = 64;
    constexpr int RROW = 36;                 // relu-tile row stride in dwords (72 ushorts)
    constexpr int RB = 64 * RROW * 4;        // 9216 B
    constexpr int WROW = K + 8;              // 72 ushorts
    constexpr int WB = M * WROW * 2;
    constexpr int CB = 64 * M * 4;
    constexpr int SMEM = (RB + WB > CB) ? (RB + WB) : CB;
    __shared__ __align__(16) char smem[SMEM];
    const int t = threadIdx.x;
    const int w = t >> 6, lane = t & 63;
    const int row0 = blockIdx.x * 64;

    // Stage W^T bf16 (phase 1 doesn't read it; barrier below covers it).
    ushort_t* WsU = (ushort_t*)(smem + RB);
    for (int i = t; i < K * M; i += THREADS_A) {
        const int k = i / M, m = i % M;
        WsU[m * WROW + k] = f2bf(W[i]);
    }

    // Phase 1: gather+relu for this wave's 8 nodes.
    unsigned* Rl = (unsigned*)smem;
    const int col2 = lane & 15;              // dword-pair within 32-dword row
    const int slot = lane >> 4;              // edge slot 0..3
    const unsigned roff = (unsigned)(col2 * 2);
    const unsigned cap = (unsigned)(N - 1);
    const int node00 = row0 + w * 8;
    // Wave-invariant bias (hoisted off the per-node chain).
    const float4 bias4 = *(const float4*)(abias + col2 * 4);
    // Row/dinv prefetch: lanes 0..9 hold row[node00+lane] (E past the end).
    int rv;
    float dvv;
    {
        const int ridx = node00 + (int)lane;
        const bool okr = ridx < N;
        rv = okr ? row[ridx] : E;
        dvv = okr ? dinv[ridx] : 0.0f;
    }
    // Prefetch node-0 chunk-0 idx (16 lanes cooperative, broadcast pattern).
    int sc = __shfl(rv, 0, 64);
    int ec = __shfl(rv, 1, 64);
    unsigned idx0 = srt[sc + col2];
#pragma unroll 1
    for (int i = 0; i < 8; ++i) {
        const int node = node00 + i;
        if (node >= N) break;
        const int start = sc, end = ec;
        unsigned idx = idx0;
        if (i < 7) {  // prefetch next node's chunk-0 idx during this node
            sc = __shfl(rv, i + 1, 64);
            ec = __shfl(rv, i + 2, 64);
            idx0 = srt[sc + col2];
        }
        // Self-loop row, issued early (independent of gathers).
        const uint2 sv = *(const uint2*)(H2 + (((unsigned)node << 5) + roff));
        f32x2 a0 = {0.0f, 0.0f}, a1 = {0.0f, 0.0f};
        int base = start;
        while (base + 16 <= end) {
            unsigned idxn = 0;
            if (base + 16 < end)  // prefetch next chunk idx before the adds
                idxn = srt[base + 16 + col2];
#pragma unroll
            for (int g = 0; g < 4; ++g) {
                const unsigned r = (unsigned)__shfl((int)idx, g * 4 + slot, 64);
                const uint2 v = *(const uint2*)(H2 + ((r << 5) + roff));
                a0 += (f32x2){bflo(v.x), bfhi(v.x)};
                a1 += (f32x2){bflo(v.y), bfhi(v.y)};
            }
            base += 16;
            idx = idxn;
        }
        const int rem = end - base;
        if (rem > 0) {
#pragma unroll
            for (int g = 0; g < 4; ++g) {
                if (g * 4 >= rem) break;               // wave-uniform
                const int e = g * 4 + slot;
                unsigned r = (unsigned)__shfl((int)idx, e, 64) & 0x1FFFFu;
                r = min(r, cap);                       // garbage past end
                uint2 v = *(const uint2*)(H2 + ((r << 5) + roff));
                const bool ok = e < rem;
                v.x = ok ? v.x : 0u;
                v.y = ok ? v.y : 0u;
                a0 += (f32x2){bflo(v.x), bfhi(v.x)};
                a1 += (f32x2){bflo(v.y), bfhi(v.y)};
            }
        }
        // Reduce across the 4 edge slots (lanes 16 apart share col2).
        a0.x += __shfl_xor(a0.x, 16, 64);
        a0.y += __shfl_xor(a0.y, 16, 64);
        a1.x += __shfl_xor(a1.x, 16, 64);
        a1.y += __shfl_xor(a1.y, 16, 64);
        a0.x += __shfl_xor(a0.x, 32, 64);
        a0.y += __shfl_xor(a0.y, 32, 64);
        a1.x += __shfl_xor(a1.x, 32, 64);
        a1.y += __shfl_xor(a1.y, 32, 64);
        const float d = __shfl(dvv, i, 64);
        if (slot == 0) {
            const float o0 = fmaxf(fmaf(a0.x + bflo(sv.x), d, bias4.x), 0.0f);
            const float o1 = fmaxf(fmaf(a0.y + bfhi(sv.x), d, bias4.y), 0.0f);
            const float o2 = fmaxf(fmaf(a1.x + bflo(sv.y), d, bias4.z), 0.0f);
            const float o3 = fmaxf(fmaf(a1.y + bfhi(sv.y), d, bias4.w), 0.0f);
            uint2 pk;
            pk.x = ((unsigned)f2bf(o1) << 16) | (unsigned)f2bf(o0);
            pk.y = ((unsigned)f2bf(o3) << 16) | (unsigned)f2bf(o2);
            *(uint2*)(Rl + (size_t)(w * 8 + i) * RROW + col2 * 2) = pk;
        }
    }
    __syncthreads();

    // Phase 2: MFMA over the relu tile. Wave = (row-strip, col-half).
    constexpr int TW = M / 32;               // col tiles per wave (64->2, 32->1)
    const int m0 = (w >> 1) * 16, lm = lane & 15, q = lane >> 4;
    const int c0 = (w & 1) * TW;
    f32x4 acc[TW];
#pragma unroll
    for (int c = 0; c < TW; ++c) acc[c] = (f32x4)0.0f;
#pragma unroll
    for (int s = 0; s < K / 32; ++s) {
        const short8 a = *(const short8*)((const ushort_t*)Rl + (size_t)(m0 + lm) * 72 + s * 32 + q * 8);
#pragma unroll
        for (int c = 0; c < TW; ++c) {
            const short8 b = *(const short8*)(WsU + (size_t)((c0 + c) * 16 + lm) * WROW + s * 32 + q * 8);
            acc[c] = __builtin_amdgcn_mfma_f32_16x16x32_bf16(a, b, acc[c], 0, 0, 0);
        }
    }
    __syncthreads();   // Rl/Ws dead; reuse as C [64][M] f32
    float* Cs = (float*)smem;
#pragma unroll
    for (int c = 0; c < TW; ++c)
#pragma unroll
        for (int r = 0; r < 4; ++r)
            Cs[(size_t)(m0 + q * 4 + r) * M + (c0 + c) * 16 + lm] = acc[c][r];
    __syncthreads();

    for (int g = t; g < 64 * M / 4; g += THREADS_A) {
        const int r = g / (M / 4);
        const int gr = row0 + r;
        if (gr >= N) continue;
        float4 o = *(const float4*)(Cs + (size_t)g * 4);
        const int col = (g % (M / 4)) * 4;
        if (MODE == 1) {
            const float d = dinv[gr];
            o.x *= d; o.y *= d; o.z *= d; o.w *= d;
            ushort4 pk = {f2bf(o.x), f2bf(o.y), f2bf(o.z), f2bf(o.w)};
            *(ushort4*)((ushort_t*)Yv + (size_t)gr * M + col) = pk;
        } else {
            o.x += fbias[col]; o.y += fbias[col + 1];
            o.z += fbias[col + 2]; o.w += fbias[col + 3];
            *(float4*)((float*)Yv + (size_t)gr * M + col) = o;
        }
    }
}

// ---- Launch ----------------------------------------------------------------

extern "C" void kernel_launch(void* const* d_in, const int* in_sizes, int n_in,
                              void* d_out, int out_size, void* d_ws, size_t ws_size,
                              hipStream_t stream) {
    const float* x   = (const float*)d_in[0];
    const int*   ei  = (const int*)d_in[1];   // [2, E] int32
    const float* W1  = (const float*)d_in[3];
    const float* b1  = (const float*)d_in[4];
    const float* W2  = (const float*)d_in[5];
    const float* b2  = (const float*)d_in[6];
    const float* Wfc = (const float*)d_in[7];
    const float* bfc = (const float*)d_in[8];
    float* out = (float*)d_out;

    const int N = in_sizes[0] / 128;
    const int E = in_sizes[1] / 2;
    const int* src = ei;
    const int* dst = ei + E;

    const int nb   = (N + BKT - 1) / BKT;     // 391 buckets
    const int nblk = (E + EPB - 1) / EPB;     // 391 edge-chunks

    // Workspace (256 B-aligned slices).
    char* p = (char*)d_ws;
    auto alloc = [&](size_t bytes) { char* r = p; p += (bytes + 255) & ~(size_t)255; return r; };
    int*      cntg   = (int*)alloc((size_t)nb * 4);
    unsigned* srt    = (unsigned*)alloc((size_t)E * 4);
    int*      row    = (int*)alloc((size_t)N * 4);     // also absorbs agg tail over-reads
    float*    dinv   = (float*)alloc((size_t)N * 4);
    ushort_t* bufH   = (ushort_t*)alloc((size_t)N * 64 * 2);   // H1 table (bf16)
    ushort_t* bufR   = (ushort_t*)alloc((size_t)N * 64 * 2);   // H2 table; doubles as stagePad
    unsigned* stagePad = (unsigned*)bufR;     // nb*CAP*4 = 12.61 MB <= 12.8 MB, dead before aggmm-1

    const int mmB = (N + 63) / 64;

    // 0) zero bucket counters (kernel, not hipMemsetAsync: graph-capture-safe).
    zeroK_kernel<<<1, BIN_T, 0, stream>>>(cntg, nb);
    // 1) fused: binA partition (blocks<nblk) || mm1 MFMA unscaled (blocks>=nblk).
    binmm_kernel<128, 64><<<nblk + mmB, THREADS_A, 0, stream>>>(
        src, dst, E, nb, nblk, cntg, stagePad, x, W1, bufH, N);
    // 2) half-bucket counting sort (2 blocks/bucket) -> srt, row, dinv; +H1 rescale.
    sortB_kernel<<<nb * 2, THREADS, 0, stream>>>(stagePad, cntg, nb, N, row, dinv, srt,
                                                 (unsigned*)bufH);
    // 3) agg layer1 + mm2 fused -> H2 table (bf16, *dinv).
    aggmm_kernel<64, 1><<<mmB, THREADS_A, 0, stream>>>(
        srt, row, dinv, (const unsigned*)bufH, b1, W2, nullptr, bufR, N, E);
    // 4) agg layer2 + fc fused -> fp32 out (+bfc).
    aggmm_kernel<32, 2><<<mmB, THREADS_A, 0, stream>>>(
        srt, row, dinv, (const unsigned*)bufR, b2, Wfc, bfc, out, N, E);
}